// Round 2
// baseline (4664.751 us; speedup 1.0000x reference)
//
#include <hip/hip_runtime.h>
#include <hip/hip_bf16.h>

#define NN 50000
#define NE 800000
#define D 128
#define NL 3
#define G3 384

typedef __attribute__((ext_vector_type(4))) float f32x4;
typedef __attribute__((ext_vector_type(8))) __bf16 bf16x8;

static __device__ __forceinline__ short f2bf(float x) {
    __hip_bfloat16 b = __float2bfloat16(x);
    return *reinterpret_cast<short*>(&b);
}
static __device__ __forceinline__ float bf2f(short s) {
    union { unsigned u; float f; } v;
    v.u = ((unsigned)(unsigned short)s) << 16;
    return v.f;
}

// ---------------------------------------------------------------------------
// Detect whether edge_index arrived as int64 (viewed as int32 pairs) or int32.
__global__ void detect_i64_kernel(const int* __restrict__ ei, int* __restrict__ flag) {
    __shared__ int any_nz;
    if (threadIdx.x == 0) any_nz = 0;
    __syncthreads();
    int v = ei[threadIdx.x * 2 + 1];
    if (v != 0) atomicOr(&any_nz, 1);
    __syncthreads();
    if (threadIdx.x == 0) *flag = (any_nz == 0) ? 1 : 0;  // 1 => int64
}

// ---------------------------------------------------------------------------
// WcT[l][g][c] = sum_j weight[l][c][j] * w_ih[g][j], stored as bf16 hi/lo.
// whh[g][c] likewise.
__global__ void precompute_weights(const float* __restrict__ weight,
                                   const float* __restrict__ w_ih,
                                   const float* __restrict__ w_hh,
                                   short* __restrict__ wct_hi, short* __restrict__ wct_lo,
                                   short* __restrict__ whh_hi, short* __restrict__ whh_lo) {
    int l = blockIdx.x / G3;
    int g = blockIdx.x % G3;
    int c = threadIdx.x;  // 0..127
    __shared__ float wih_row[D];
    wih_row[c] = w_ih[g * D + c];
    __syncthreads();
    const float* wrow = weight + ((long long)l * D + c) * D;  // weight[l][c][:]
    float acc = 0.f;
#pragma unroll 8
    for (int j = 0; j < D; ++j) acc += wrow[j] * wih_row[j];
    long long idx = ((long long)l * G3 + g) * D + c;
    short hi = f2bf(acc);
    wct_hi[idx] = hi;
    wct_lo[idx] = f2bf(acc - bf2f(hi));
    if (l == 0) {
        float w = w_hh[g * D + c];
        short h1 = f2bf(w);
        whh_hi[g * D + c] = h1;
        whh_lo[g * D + c] = f2bf(w - bf2f(h1));
    }
}

// ---------------------------------------------------------------------------
// agg[dst] += h[src] over all edges. 32 threads per edge (4 floats each).
__global__ void scatter_add_kernel(const float* __restrict__ h,
                                   const int* __restrict__ ei,
                                   const int* __restrict__ flag,
                                   float* __restrict__ agg) {
    long long idx = (long long)blockIdx.x * blockDim.x + threadIdx.x;
    int e = (int)(idx >> 5);
    if (e >= NE) return;
    int p = (int)(idx & 31);
    int src, dst;
    if (*flag) {  // int64 storage: low words at even offsets
        src = ei[2LL * e];
        dst = ei[2LL * (NE + e)];
    } else {
        src = ei[e];
        dst = ei[NE + e];
    }
    f32x4 v = *(const f32x4*)(h + (long long)src * D + p * 4);
    float* dp = agg + (long long)dst * D + p * 4;
    atomicAdd(dp + 0, v[0]);
    atomicAdd(dp + 1, v[1]);
    atomicAdd(dp + 2, v[2]);
    atomicAdd(dp + 3, v[3]);
}

// ---------------------------------------------------------------------------
// Fused GRU. Each block owns 64 FULL rows (all 128 cols) -> in-place h update
// is race-free. bf16 hi/lo split GEMM (3 MFMA terms) for ~fp16+ precision.
#define TM 64
#define MFMA_B16 __builtin_amdgcn_mfma_f32_16x16x32_bf16
__global__ __launch_bounds__(256) void gru_fused_kernel(
    const float* __restrict__ agg, float* __restrict__ h,
    const short* __restrict__ wct_hi, const short* __restrict__ wct_lo,
    const short* __restrict__ whh_hi, const short* __restrict__ whh_lo,
    const float* __restrict__ b_ih, const float* __restrict__ b_hh) {
    __shared__ short lds_ahi[TM * D];
    __shared__ short lds_alo[TM * D];
    __shared__ short lds_hhi[TM * D];
    __shared__ short lds_hlo[TM * D];
    const int tid = threadIdx.x;
    const int m0 = blockIdx.x * TM;

    // Stage agg & h tiles to LDS as bf16 hi/lo, XOR-swizzled (G4).
#pragma unroll
    for (int it = 0; it < 8; ++it) {
        int flat = it * 1024 + tid * 4;  // element index in 64x128 tile
        int row = flat >> 7;
        int col = flat & 127;
        int grow = m0 + row;
        f32x4 va = {0, 0, 0, 0}, vh = {0, 0, 0, 0};
        if (grow < NN) {
            va = *(const f32x4*)(agg + (long long)grow * D + col);
            vh = *(const f32x4*)(h + (long long)grow * D + col);
        }
        union { short s[4]; unsigned long long u; } ahi, alo, hhi, hlo;
#pragma unroll
        for (int q = 0; q < 4; ++q) {
            short x = f2bf(va[q]);
            ahi.s[q] = x;
            alo.s[q] = f2bf(va[q] - bf2f(x));
            short y = f2bf(vh[q]);
            hhi.s[q] = y;
            hlo.s[q] = f2bf(vh[q] - bf2f(y));
        }
        int byte = ((row * D + col) * 2) ^ ((row & 7) << 4);
        *(unsigned long long*)((char*)lds_ahi + byte) = ahi.u;
        *(unsigned long long*)((char*)lds_alo + byte) = alo.u;
        *(unsigned long long*)((char*)lds_hhi + byte) = hhi.u;
        *(unsigned long long*)((char*)lds_hlo + byte) = hlo.u;
    }
    __syncthreads();

    const int lane = tid & 63;
    const int wv = tid >> 6;
    const int fr = lane & 15;  // A row / B col / D col
    const int kg = lane >> 4;  // k-group

    // Persistent A fragments (own 16 rows, all K), hi/lo.
    bf16x8 fa_hi[4], fa_lo[4], fh_hi[4], fh_lo[4];
    const int arow = wv * 16 + fr;
#pragma unroll
    for (int ks = 0; ks < 4; ++ks) {
        int k0 = ks * 32 + kg * 8;
        int ab = ((arow * D + k0) * 2) ^ ((arow & 7) << 4);
        fa_hi[ks] = *(const bf16x8*)((const char*)lds_ahi + ab);
        fa_lo[ks] = *(const bf16x8*)((const char*)lds_alo + ab);
        fh_hi[ks] = *(const bf16x8*)((const char*)lds_hhi + ab);
        fh_lo[ks] = *(const bf16x8*)((const char*)lds_hlo + ab);
    }

    // Loop over 8 d-tiles of 16 output cols.
#pragma unroll 1
    for (int dt = 0; dt < 8; ++dt) {
        const int g = dt * 16 + fr;  // output col / weight row (gate r); z:+128, n:+256
        f32x4 a_ir = {0, 0, 0, 0}, a_iz = {0, 0, 0, 0}, a_in = {0, 0, 0, 0};
        f32x4 a_hr = {0, 0, 0, 0}, a_hz = {0, 0, 0, 0}, a_hn = {0, 0, 0, 0};
#pragma unroll
        for (int ks = 0; ks < 4; ++ks) {
            int k0 = ks * 32 + kg * 8;
            const long long rR = (long long)(g)*D + k0;
            const long long rZ = (long long)(128 + g) * D + k0;
            const long long rN = (long long)(256 + g) * D + k0;
            bf16x8 birh = *(const bf16x8*)(wct_hi + rR);
            bf16x8 birl = *(const bf16x8*)(wct_lo + rR);
            bf16x8 bizh = *(const bf16x8*)(wct_hi + rZ);
            bf16x8 bizl = *(const bf16x8*)(wct_lo + rZ);
            bf16x8 binh = *(const bf16x8*)(wct_hi + rN);
            bf16x8 binl = *(const bf16x8*)(wct_lo + rN);
            bf16x8 bhrh = *(const bf16x8*)(whh_hi + rR);
            bf16x8 bhrl = *(const bf16x8*)(whh_lo + rR);
            bf16x8 bhzh = *(const bf16x8*)(whh_hi + rZ);
            bf16x8 bhzl = *(const bf16x8*)(whh_lo + rZ);
            bf16x8 bhnh = *(const bf16x8*)(whh_hi + rN);
            bf16x8 bhnl = *(const bf16x8*)(whh_lo + rN);
            a_ir = MFMA_B16(fa_hi[ks], birh, a_ir, 0, 0, 0);
            a_ir = MFMA_B16(fa_lo[ks], birh, a_ir, 0, 0, 0);
            a_ir = MFMA_B16(fa_hi[ks], birl, a_ir, 0, 0, 0);
            a_iz = MFMA_B16(fa_hi[ks], bizh, a_iz, 0, 0, 0);
            a_iz = MFMA_B16(fa_lo[ks], bizh, a_iz, 0, 0, 0);
            a_iz = MFMA_B16(fa_hi[ks], bizl, a_iz, 0, 0, 0);
            a_in = MFMA_B16(fa_hi[ks], binh, a_in, 0, 0, 0);
            a_in = MFMA_B16(fa_lo[ks], binh, a_in, 0, 0, 0);
            a_in = MFMA_B16(fa_hi[ks], binl, a_in, 0, 0, 0);
            a_hr = MFMA_B16(fh_hi[ks], bhrh, a_hr, 0, 0, 0);
            a_hr = MFMA_B16(fh_lo[ks], bhrh, a_hr, 0, 0, 0);
            a_hr = MFMA_B16(fh_hi[ks], bhrl, a_hr, 0, 0, 0);
            a_hz = MFMA_B16(fh_hi[ks], bhzh, a_hz, 0, 0, 0);
            a_hz = MFMA_B16(fh_lo[ks], bhzh, a_hz, 0, 0, 0);
            a_hz = MFMA_B16(fh_hi[ks], bhzl, a_hz, 0, 0, 0);
            a_hn = MFMA_B16(fh_hi[ks], bhnh, a_hn, 0, 0, 0);
            a_hn = MFMA_B16(fh_lo[ks], bhnh, a_hn, 0, 0, 0);
            a_hn = MFMA_B16(fh_hi[ks], bhnl, a_hn, 0, 0, 0);
        }
        // Epilogue: C/D layout col = lane&15, row = (lane>>4)*4 + j  [m89/m91]
        const int d = g;
        float bir = b_ih[d], biz = b_ih[128 + d], bin_ = b_ih[256 + d];
        float bhr = b_hh[d], bhz = b_hh[128 + d], bhn = b_hh[256 + d];
#pragma unroll
        for (int j = 0; j < 4; ++j) {
            int row = m0 + wv * 16 + kg * 4 + j;
            if (row >= NN) continue;
            float ir = a_ir[j] + bir, iz = a_iz[j] + biz, in_ = a_in[j] + bin_;
            float hr = a_hr[j] + bhr, hz = a_hz[j] + bhz, hn = a_hn[j] + bhn;
            float r = 1.f / (1.f + __expf(-(ir + hr)));
            float zz = 1.f / (1.f + __expf(-(iz + hz)));
            float nn = tanhf(in_ + r * hn);
            long long off = (long long)row * D + d;
            float hold = h[off];
            h[off] = (1.f - zz) * nn + zz * hold;
        }
    }
}

// ---------------------------------------------------------------------------
extern "C" void kernel_launch(void* const* d_in, const int* in_sizes, int n_in,
                              void* d_out, int out_size, void* d_ws, size_t ws_size,
                              hipStream_t stream) {
    const float* z = (const float*)d_in[0];
    const int* ei = (const int*)d_in[1];
    const float* weight = (const float*)d_in[2];
    const float* w_ih = (const float*)d_in[3];
    const float* w_hh = (const float*)d_in[4];
    const float* b_ih = (const float*)d_in[5];
    const float* b_hh = (const float*)d_in[6];
    float* h = (float*)d_out;

    char* ws = (char*)d_ws;
    short* wct_hi = (short*)(ws + 0);            // 294912 B
    short* wct_lo = (short*)(ws + 294912);       // 294912 B
    short* whh_hi = (short*)(ws + 589824);       //  98304 B
    short* whh_lo = (short*)(ws + 688128);       //  98304 B
    int* flag = (int*)(ws + 786432);             //    256 B
    float* agg = (float*)(ws + 786688);          // 25.6 MB

    // h <- z
    hipMemcpyAsync(h, z, (size_t)NN * D * sizeof(float), hipMemcpyDeviceToDevice, stream);

    detect_i64_kernel<<<1, 256, 0, stream>>>(ei, flag);
    precompute_weights<<<NL * G3, 128, 0, stream>>>(weight, w_ih, w_hh,
                                                    wct_hi, wct_lo, whh_hi, whh_lo);

    for (int l = 0; l < NL; ++l) {
        hipMemsetAsync(agg, 0, (size_t)NN * D * sizeof(float), stream);
        long long sthreads = (long long)NE * 32;
        int sblocks = (int)((sthreads + 255) / 256);
        scatter_add_kernel<<<sblocks, 256, 0, stream>>>(h, ei, flag, agg);
        long long woff = (long long)l * G3 * D;
        gru_fused_kernel<<<(NN + TM - 1) / TM, 256, 0, stream>>>(
            agg, h, wct_hi + woff, wct_lo + woff, whh_hi, whh_lo, b_ih, b_hh);
    }
}

// Round 3
// 1012.848 us; speedup vs baseline: 4.6056x; 4.6056x over previous
//
#include <hip/hip_runtime.h>
#include <hip/hip_bf16.h>

#define NN 50000
#define NE 800000
#define D 128
#define NL 3
#define G3 384

typedef __attribute__((ext_vector_type(4))) float f32x4;
typedef __attribute__((ext_vector_type(2))) float f32x2;
typedef __attribute__((ext_vector_type(8))) __bf16 bf16x8;

static __device__ __forceinline__ short f2bf(float x) {
    __hip_bfloat16 b = __float2bfloat16(x);
    return *reinterpret_cast<short*>(&b);
}
static __device__ __forceinline__ float bf2f(short s) {
    union { unsigned u; float f; } v;
    v.u = ((unsigned)(unsigned short)s) << 16;
    return v.f;
}

// ---------------------------------------------------------------------------
// Detect whether edge_index arrived as int64 (viewed as int32 pairs) or int32.
__global__ void detect_i64_kernel(const int* __restrict__ ei, int* __restrict__ flag) {
    __shared__ int any_nz;
    if (threadIdx.x == 0) any_nz = 0;
    __syncthreads();
    int v = ei[threadIdx.x * 2 + 1];
    if (v != 0) atomicOr(&any_nz, 1);
    __syncthreads();
    if (threadIdx.x == 0) *flag = (any_nz == 0) ? 1 : 0;  // 1 => int64
}

static __device__ __forceinline__ void load_edge(const int* ei, const int* flag, int e,
                                                 int& src, int& dst) {
    if (*flag) {  // int64 storage: low words at even offsets
        src = ei[2LL * e];
        dst = ei[2LL * (NE + e)];
    } else {
        src = ei[e];
        dst = ei[NE + e];
    }
}

// ---------------------------------------------------------------------------
// CSR build: histogram -> single-block scan -> fill.
__global__ void hist_kernel(const int* __restrict__ ei, const int* __restrict__ flag,
                            int* __restrict__ counts) {
    int e = blockIdx.x * blockDim.x + threadIdx.x;
    if (e >= NE) return;
    int src, dst;
    load_edge(ei, flag, e, src, dst);
    atomicAdd(counts + dst, 1);
}

#define SCAN_T 1024
#define CHUNK 49  // 1024*49 >= 50000
__global__ __launch_bounds__(SCAN_T) void scan_kernel(const int* __restrict__ counts,
                                                      int* __restrict__ row_start,
                                                      int* __restrict__ cursor) {
    __shared__ int lds[SCAN_T];
    const int tid = threadIdx.x;
    const int base = tid * CHUNK;
    int s = 0;
#pragma unroll
    for (int i = 0; i < CHUNK; ++i) {
        int idx = base + i;
        if (idx < NN) s += counts[idx];
    }
    lds[tid] = s;
    __syncthreads();
    for (int off = 1; off < SCAN_T; off <<= 1) {
        int v = (tid >= off) ? lds[tid - off] : 0;
        __syncthreads();
        lds[tid] += v;
        __syncthreads();
    }
    int start = lds[tid] - s;  // exclusive prefix
#pragma unroll
    for (int i = 0; i < CHUNK; ++i) {
        int idx = base + i;
        if (idx < NN) {
            row_start[idx] = start;
            cursor[idx] = start;
            start += counts[idx];
        }
    }
    if (tid == SCAN_T - 1) row_start[NN] = lds[SCAN_T - 1];
}

__global__ void fill_kernel(const int* __restrict__ ei, const int* __restrict__ flag,
                            int* __restrict__ cursor, int* __restrict__ csr_src) {
    int e = blockIdx.x * blockDim.x + threadIdx.x;
    if (e >= NE) return;
    int src, dst;
    load_edge(ei, flag, e, src, dst);
    int slot = atomicAdd(cursor + dst, 1);
    csr_src[slot] = src;
}

// ---------------------------------------------------------------------------
// Gather: one wave per dst row; agg[dst] = sum_{e in CSR row} h[src_e].
// h (25.6 MB) is L2/L3-resident -> cache-gather, no atomics, coalesced write.
__global__ __launch_bounds__(256) void gather_kernel(const float* __restrict__ h,
                                                     const int* __restrict__ row_start,
                                                     const int* __restrict__ csr_src,
                                                     float* __restrict__ agg) {
    int row = blockIdx.x * 4 + (threadIdx.x >> 6);
    if (row >= NN) return;
    int lane = threadIdx.x & 63;
    int beg = row_start[row], end = row_start[row + 1];
    f32x2 acc0 = {0.f, 0.f}, acc1 = {0.f, 0.f};
    int e = beg;
    for (; e + 1 < end; e += 2) {
        int s0 = csr_src[e], s1 = csr_src[e + 1];
        f32x2 v0 = *(const f32x2*)(h + (long long)s0 * D + lane * 2);
        f32x2 v1 = *(const f32x2*)(h + (long long)s1 * D + lane * 2);
        acc0 += v0;
        acc1 += v1;
    }
    if (e < end) {
        int s0 = csr_src[e];
        acc0 += *(const f32x2*)(h + (long long)s0 * D + lane * 2);
    }
    *(f32x2*)(agg + (long long)row * D + lane * 2) = acc0 + acc1;
}

// ---------------------------------------------------------------------------
// WcT[l][g][c] = sum_j weight[l][c][j] * w_ih[g][j], stored as bf16 hi/lo.
__global__ void precompute_weights(const float* __restrict__ weight,
                                   const float* __restrict__ w_ih,
                                   const float* __restrict__ w_hh,
                                   short* __restrict__ wct_hi, short* __restrict__ wct_lo,
                                   short* __restrict__ whh_hi, short* __restrict__ whh_lo) {
    int l = blockIdx.x / G3;
    int g = blockIdx.x % G3;
    int c = threadIdx.x;  // 0..127
    __shared__ float wih_row[D];
    wih_row[c] = w_ih[g * D + c];
    __syncthreads();
    const float* wrow = weight + ((long long)l * D + c) * D;  // weight[l][c][:]
    float acc = 0.f;
#pragma unroll 8
    for (int j = 0; j < D; ++j) acc += wrow[j] * wih_row[j];
    long long idx = ((long long)l * G3 + g) * D + c;
    short hi = f2bf(acc);
    wct_hi[idx] = hi;
    wct_lo[idx] = f2bf(acc - bf2f(hi));
    if (l == 0) {
        float w = w_hh[g * D + c];
        short h1 = f2bf(w);
        whh_hi[g * D + c] = h1;
        whh_lo[g * D + c] = f2bf(w - bf2f(h1));
    }
}

// ---------------------------------------------------------------------------
// Fused GRU. Each block owns 64 FULL rows (all 128 cols) -> in-place h update
// is race-free. bf16 hi/lo split GEMM (3 MFMA terms) for ~fp16+ precision.
#define TM 64
#define MFMA_B16 __builtin_amdgcn_mfma_f32_16x16x32_bf16
__global__ __launch_bounds__(256) void gru_fused_kernel(
    const float* __restrict__ agg, float* __restrict__ h,
    const short* __restrict__ wct_hi, const short* __restrict__ wct_lo,
    const short* __restrict__ whh_hi, const short* __restrict__ whh_lo,
    const float* __restrict__ b_ih, const float* __restrict__ b_hh) {
    __shared__ short lds_ahi[TM * D];
    __shared__ short lds_alo[TM * D];
    __shared__ short lds_hhi[TM * D];
    __shared__ short lds_hlo[TM * D];
    const int tid = threadIdx.x;
    const int m0 = blockIdx.x * TM;

    // Stage agg & h tiles to LDS as bf16 hi/lo, XOR-swizzled (G4).
#pragma unroll
    for (int it = 0; it < 8; ++it) {
        int flat = it * 1024 + tid * 4;  // element index in 64x128 tile
        int row = flat >> 7;
        int col = flat & 127;
        int grow = m0 + row;
        f32x4 va = {0, 0, 0, 0}, vh = {0, 0, 0, 0};
        if (grow < NN) {
            va = *(const f32x4*)(agg + (long long)grow * D + col);
            vh = *(const f32x4*)(h + (long long)grow * D + col);
        }
        union { short s[4]; unsigned long long u; } ahi, alo, hhi, hlo;
#pragma unroll
        for (int q = 0; q < 4; ++q) {
            short x = f2bf(va[q]);
            ahi.s[q] = x;
            alo.s[q] = f2bf(va[q] - bf2f(x));
            short y = f2bf(vh[q]);
            hhi.s[q] = y;
            hlo.s[q] = f2bf(vh[q] - bf2f(y));
        }
        int byte = ((row * D + col) * 2) ^ ((row & 7) << 4);
        *(unsigned long long*)((char*)lds_ahi + byte) = ahi.u;
        *(unsigned long long*)((char*)lds_alo + byte) = alo.u;
        *(unsigned long long*)((char*)lds_hhi + byte) = hhi.u;
        *(unsigned long long*)((char*)lds_hlo + byte) = hlo.u;
    }
    __syncthreads();

    const int lane = tid & 63;
    const int wv = tid >> 6;
    const int fr = lane & 15;  // A row / B col / D col
    const int kg = lane >> 4;  // k-group

    // Persistent A fragments (own 16 rows, all K), hi/lo.
    bf16x8 fa_hi[4], fa_lo[4], fh_hi[4], fh_lo[4];
    const int arow = wv * 16 + fr;
#pragma unroll
    for (int ks = 0; ks < 4; ++ks) {
        int k0 = ks * 32 + kg * 8;
        int ab = ((arow * D + k0) * 2) ^ ((arow & 7) << 4);
        fa_hi[ks] = *(const bf16x8*)((const char*)lds_ahi + ab);
        fa_lo[ks] = *(const bf16x8*)((const char*)lds_alo + ab);
        fh_hi[ks] = *(const bf16x8*)((const char*)lds_hhi + ab);
        fh_lo[ks] = *(const bf16x8*)((const char*)lds_hlo + ab);
    }

    // Loop over 8 d-tiles of 16 output cols.
#pragma unroll 1
    for (int dt = 0; dt < 8; ++dt) {
        const int g = dt * 16 + fr;  // output col / weight row (gate r); z:+128, n:+256
        f32x4 a_ir = {0, 0, 0, 0}, a_iz = {0, 0, 0, 0}, a_in = {0, 0, 0, 0};
        f32x4 a_hr = {0, 0, 0, 0}, a_hz = {0, 0, 0, 0}, a_hn = {0, 0, 0, 0};
#pragma unroll
        for (int ks = 0; ks < 4; ++ks) {
            int k0 = ks * 32 + kg * 8;
            const long long rR = (long long)(g)*D + k0;
            const long long rZ = (long long)(128 + g) * D + k0;
            const long long rN = (long long)(256 + g) * D + k0;
            bf16x8 birh = *(const bf16x8*)(wct_hi + rR);
            bf16x8 birl = *(const bf16x8*)(wct_lo + rR);
            bf16x8 bizh = *(const bf16x8*)(wct_hi + rZ);
            bf16x8 bizl = *(const bf16x8*)(wct_lo + rZ);
            bf16x8 binh = *(const bf16x8*)(wct_hi + rN);
            bf16x8 binl = *(const bf16x8*)(wct_lo + rN);
            bf16x8 bhrh = *(const bf16x8*)(whh_hi + rR);
            bf16x8 bhrl = *(const bf16x8*)(whh_lo + rR);
            bf16x8 bhzh = *(const bf16x8*)(whh_hi + rZ);
            bf16x8 bhzl = *(const bf16x8*)(whh_lo + rZ);
            bf16x8 bhnh = *(const bf16x8*)(whh_hi + rN);
            bf16x8 bhnl = *(const bf16x8*)(whh_lo + rN);
            a_ir = MFMA_B16(fa_hi[ks], birh, a_ir, 0, 0, 0);
            a_ir = MFMA_B16(fa_lo[ks], birh, a_ir, 0, 0, 0);
            a_ir = MFMA_B16(fa_hi[ks], birl, a_ir, 0, 0, 0);
            a_iz = MFMA_B16(fa_hi[ks], bizh, a_iz, 0, 0, 0);
            a_iz = MFMA_B16(fa_lo[ks], bizh, a_iz, 0, 0, 0);
            a_iz = MFMA_B16(fa_hi[ks], bizl, a_iz, 0, 0, 0);
            a_in = MFMA_B16(fa_hi[ks], binh, a_in, 0, 0, 0);
            a_in = MFMA_B16(fa_lo[ks], binh, a_in, 0, 0, 0);
            a_in = MFMA_B16(fa_hi[ks], binl, a_in, 0, 0, 0);
            a_hr = MFMA_B16(fh_hi[ks], bhrh, a_hr, 0, 0, 0);
            a_hr = MFMA_B16(fh_lo[ks], bhrh, a_hr, 0, 0, 0);
            a_hr = MFMA_B16(fh_hi[ks], bhrl, a_hr, 0, 0, 0);
            a_hz = MFMA_B16(fh_hi[ks], bhzh, a_hz, 0, 0, 0);
            a_hz = MFMA_B16(fh_lo[ks], bhzh, a_hz, 0, 0, 0);
            a_hz = MFMA_B16(fh_hi[ks], bhzl, a_hz, 0, 0, 0);
            a_hn = MFMA_B16(fh_hi[ks], bhnh, a_hn, 0, 0, 0);
            a_hn = MFMA_B16(fh_lo[ks], bhnh, a_hn, 0, 0, 0);
            a_hn = MFMA_B16(fh_hi[ks], bhnl, a_hn, 0, 0, 0);
        }
        // Epilogue: C/D layout col = lane&15, row = (lane>>4)*4 + j  [m89/m91]
        const int d = g;
        float bir = b_ih[d], biz = b_ih[128 + d], bin_ = b_ih[256 + d];
        float bhr = b_hh[d], bhz = b_hh[128 + d], bhn = b_hh[256 + d];
#pragma unroll
        for (int j = 0; j < 4; ++j) {
            int row = m0 + wv * 16 + kg * 4 + j;
            if (row >= NN) continue;
            float ir = a_ir[j] + bir, iz = a_iz[j] + biz, in_ = a_in[j] + bin_;
            float hr = a_hr[j] + bhr, hz = a_hz[j] + bhz, hn = a_hn[j] + bhn;
            float r = 1.f / (1.f + __expf(-(ir + hr)));
            float zz = 1.f / (1.f + __expf(-(iz + hz)));
            float nn = tanhf(in_ + r * hn);
            long long off = (long long)row * D + d;
            float hold = h[off];
            h[off] = (1.f - zz) * nn + zz * hold;
        }
    }
}

// ---------------------------------------------------------------------------
extern "C" void kernel_launch(void* const* d_in, const int* in_sizes, int n_in,
                              void* d_out, int out_size, void* d_ws, size_t ws_size,
                              hipStream_t stream) {
    const float* z = (const float*)d_in[0];
    const int* ei = (const int*)d_in[1];
    const float* weight = (const float*)d_in[2];
    const float* w_ih = (const float*)d_in[3];
    const float* w_hh = (const float*)d_in[4];
    const float* b_ih = (const float*)d_in[5];
    const float* b_hh = (const float*)d_in[6];
    float* h = (float*)d_out;

    char* ws = (char*)d_ws;
    size_t off = 0;
    short* wct_hi = (short*)(ws + off); off += 294912;
    short* wct_lo = (short*)(ws + off); off += 294912;
    short* whh_hi = (short*)(ws + off); off += 98304;
    short* whh_lo = (short*)(ws + off); off += 98304;
    int* flag     = (int*)(ws + off);   off += 256;
    int* counts   = (int*)(ws + off);   off += (size_t)NN * 4;
    int* cursor   = (int*)(ws + off);   off += (size_t)NN * 4;
    int* row_start= (int*)(ws + off);   off += (size_t)(NN + 16) * 4;
    int* csr_src  = (int*)(ws + off);   off += (size_t)NE * 4;
    float* agg    = (float*)(ws + off); // 25.6 MB

    // h <- z
    hipMemcpyAsync(h, z, (size_t)NN * D * sizeof(float), hipMemcpyDeviceToDevice, stream);

    detect_i64_kernel<<<1, 256, 0, stream>>>(ei, flag);
    hipMemsetAsync(counts, 0, (size_t)NN * 4, stream);
    hist_kernel<<<(NE + 255) / 256, 256, 0, stream>>>(ei, flag, counts);
    scan_kernel<<<1, SCAN_T, 0, stream>>>(counts, row_start, cursor);
    fill_kernel<<<(NE + 255) / 256, 256, 0, stream>>>(ei, flag, cursor, csr_src);
    precompute_weights<<<NL * G3, 128, 0, stream>>>(weight, w_ih, w_hh,
                                                    wct_hi, wct_lo, whh_hi, whh_lo);

    for (int l = 0; l < NL; ++l) {
        gather_kernel<<<(NN + 3) / 4, 256, 0, stream>>>(h, row_start, csr_src, agg);
        long long woff = (long long)l * G3 * D;
        gru_fused_kernel<<<(NN + TM - 1) / TM, 256, 0, stream>>>(
            agg, h, wct_hi + woff, wct_lo + woff, whh_hi, whh_lo, b_ih, b_hh);
    }
}

// Round 4
// 886.141 us; speedup vs baseline: 5.2641x; 1.1430x over previous
//
#include <hip/hip_runtime.h>
#include <hip/hip_bf16.h>

#define NN 50000
#define NE 800000
#define D 128
#define NL 3
#define G3 384

typedef __attribute__((ext_vector_type(4))) float f32x4;
typedef __attribute__((ext_vector_type(2))) float f32x2;
typedef __attribute__((ext_vector_type(8))) __bf16 bf16x8;

static __device__ __forceinline__ unsigned short f2bf(float x) {
    __hip_bfloat16 b = __float2bfloat16(x);
    return *reinterpret_cast<unsigned short*>(&b);
}
static __device__ __forceinline__ float bf2f(unsigned short s) {
    union { unsigned u; float f; } v;
    v.u = ((unsigned)s) << 16;
    return v.f;
}
static __device__ __forceinline__ float lo_of(unsigned u) {  // low ushort as bf16
    union { unsigned x; float f; } v;
    v.x = u << 16;
    return v.f;
}
static __device__ __forceinline__ float hi_of(unsigned u) {  // high ushort as bf16
    union { unsigned x; float f; } v;
    v.x = u & 0xFFFF0000u;
    return v.f;
}

// ---------------------------------------------------------------------------
// Detect whether edge_index arrived as int64 (viewed as int32 pairs) or int32.
__global__ void detect_i64_kernel(const int* __restrict__ ei, int* __restrict__ flag) {
    __shared__ int any_nz;
    if (threadIdx.x == 0) any_nz = 0;
    __syncthreads();
    int v = ei[threadIdx.x * 2 + 1];
    if (v != 0) atomicOr(&any_nz, 1);
    __syncthreads();
    if (threadIdx.x == 0) *flag = (any_nz == 0) ? 1 : 0;  // 1 => int64
}

static __device__ __forceinline__ void load_edge(const int* ei, const int* flag, int e,
                                                 int& src, int& dst) {
    if (*flag) {
        src = ei[2LL * e];
        dst = ei[2LL * (NE + e)];
    } else {
        src = ei[e];
        dst = ei[NE + e];
    }
}

// ---------------------------------------------------------------------------
// CSR build: histogram -> single-block scan -> fill.
__global__ void hist_kernel(const int* __restrict__ ei, const int* __restrict__ flag,
                            int* __restrict__ counts) {
    int e = blockIdx.x * blockDim.x + threadIdx.x;
    if (e >= NE) return;
    int src, dst;
    load_edge(ei, flag, e, src, dst);
    atomicAdd(counts + dst, 1);
}

#define SCAN_T 1024
#define CHUNK 49  // 1024*49 >= 50000
__global__ __launch_bounds__(SCAN_T) void scan_kernel(const int* __restrict__ counts,
                                                      int* __restrict__ row_start,
                                                      int* __restrict__ cursor) {
    __shared__ int lds[SCAN_T];
    const int tid = threadIdx.x;
    const int base = tid * CHUNK;
    int s = 0;
#pragma unroll
    for (int i = 0; i < CHUNK; ++i) {
        int idx = base + i;
        if (idx < NN) s += counts[idx];
    }
    lds[tid] = s;
    __syncthreads();
    for (int off = 1; off < SCAN_T; off <<= 1) {
        int v = (tid >= off) ? lds[tid - off] : 0;
        __syncthreads();
        lds[tid] += v;
        __syncthreads();
    }
    int start = lds[tid] - s;  // exclusive prefix
#pragma unroll
    for (int i = 0; i < CHUNK; ++i) {
        int idx = base + i;
        if (idx < NN) {
            row_start[idx] = start;
            cursor[idx] = start;
            start += counts[idx];
        }
    }
    if (tid == SCAN_T - 1) row_start[NN] = lds[SCAN_T - 1];
}

__global__ void fill_kernel(const int* __restrict__ ei, const int* __restrict__ flag,
                            int* __restrict__ cursor, int* __restrict__ csr_src) {
    int e = blockIdx.x * blockDim.x + threadIdx.x;
    if (e >= NE) return;
    int src, dst;
    load_edge(ei, flag, e, src, dst);
    int slot = atomicAdd(cursor + dst, 1);
    csr_src[slot] = src;
}

// ---------------------------------------------------------------------------
// init: h_hi/h_lo <- split(z). One thread = 2 elements.
__global__ void init_h_kernel(const float* __restrict__ z,
                              unsigned short* __restrict__ h_hi,
                              unsigned short* __restrict__ h_lo) {
    long long i = (long long)blockIdx.x * blockDim.x + threadIdx.x;
    if (i * 2 >= (long long)NN * D) return;
    f32x2 v = *(const f32x2*)(z + i * 2);
    unsigned short h0 = f2bf(v[0]), h1 = f2bf(v[1]);
    unsigned short l0 = f2bf(v[0] - bf2f(h0)), l1 = f2bf(v[1] - bf2f(h1));
    *(unsigned*)(h_hi + i * 2) = (unsigned)h0 | ((unsigned)h1 << 16);
    *(unsigned*)(h_lo + i * 2) = (unsigned)l0 | ((unsigned)l1 << 16);
}

// finalize: out <- h_hi + h_lo (f32)
__global__ void finalize_kernel(const unsigned short* __restrict__ h_hi,
                                const unsigned short* __restrict__ h_lo,
                                float* __restrict__ out) {
    long long i = (long long)blockIdx.x * blockDim.x + threadIdx.x;
    if (i * 2 >= (long long)NN * D) return;
    unsigned uh = *(const unsigned*)(h_hi + i * 2);
    unsigned ul = *(const unsigned*)(h_lo + i * 2);
    f32x2 o;
    o[0] = lo_of(uh) + lo_of(ul);
    o[1] = hi_of(uh) + hi_of(ul);
    *(f32x2*)(out + i * 2) = o;
}

// ---------------------------------------------------------------------------
// Gather: one wave per dst row; agg[dst] = sum h[src]. hi/lo in, hi/lo out.
__global__ __launch_bounds__(256) void gather_kernel(
    const unsigned short* __restrict__ h_hi, const unsigned short* __restrict__ h_lo,
    const int* __restrict__ row_start, const int* __restrict__ csr_src,
    unsigned short* __restrict__ agg_hi, unsigned short* __restrict__ agg_lo) {
    int row = blockIdx.x * 4 + (threadIdx.x >> 6);
    if (row >= NN) return;
    int lane = threadIdx.x & 63;  // covers cols 2*lane, 2*lane+1
    int beg = row_start[row], end = row_start[row + 1];
    float a0 = 0.f, a1 = 0.f, b0 = 0.f, b1 = 0.f;
    int e = beg;
    for (; e + 1 < end; e += 2) {
        int s0 = csr_src[e], s1 = csr_src[e + 1];
        unsigned u0h = *(const unsigned*)(h_hi + (long long)s0 * D + lane * 2);
        unsigned u0l = *(const unsigned*)(h_lo + (long long)s0 * D + lane * 2);
        unsigned u1h = *(const unsigned*)(h_hi + (long long)s1 * D + lane * 2);
        unsigned u1l = *(const unsigned*)(h_lo + (long long)s1 * D + lane * 2);
        a0 += lo_of(u0h) + lo_of(u0l);
        a1 += hi_of(u0h) + hi_of(u0l);
        b0 += lo_of(u1h) + lo_of(u1l);
        b1 += hi_of(u1h) + hi_of(u1l);
    }
    if (e < end) {
        int s0 = csr_src[e];
        unsigned u0h = *(const unsigned*)(h_hi + (long long)s0 * D + lane * 2);
        unsigned u0l = *(const unsigned*)(h_lo + (long long)s0 * D + lane * 2);
        a0 += lo_of(u0h) + lo_of(u0l);
        a1 += hi_of(u0h) + hi_of(u0l);
    }
    float c0 = a0 + b0, c1 = a1 + b1;
    unsigned short h0 = f2bf(c0), h1 = f2bf(c1);
    unsigned short l0 = f2bf(c0 - bf2f(h0)), l1 = f2bf(c1 - bf2f(h1));
    long long off = (long long)row * D + lane * 2;
    *(unsigned*)(agg_hi + off) = (unsigned)h0 | ((unsigned)h1 << 16);
    *(unsigned*)(agg_lo + off) = (unsigned)l0 | ((unsigned)l1 << 16);
}

// ---------------------------------------------------------------------------
// WcT[l][g][c] = sum_j weight[l][c][j] * w_ih[g][j], bf16 hi/lo; whh hi only.
__global__ void precompute_weights(const float* __restrict__ weight,
                                   const float* __restrict__ w_ih,
                                   const float* __restrict__ w_hh,
                                   unsigned short* __restrict__ wct_hi,
                                   unsigned short* __restrict__ wct_lo,
                                   unsigned short* __restrict__ whh_hi) {
    int l = blockIdx.x / G3;
    int g = blockIdx.x % G3;
    int c = threadIdx.x;  // 0..127
    __shared__ float wih_row[D];
    wih_row[c] = w_ih[g * D + c];
    __syncthreads();
    const float* wrow = weight + ((long long)l * D + c) * D;
    float acc = 0.f;
#pragma unroll 8
    for (int j = 0; j < D; ++j) acc += wrow[j] * wih_row[j];
    long long idx = ((long long)l * G3 + g) * D + c;
    unsigned short hi = f2bf(acc);
    wct_hi[idx] = hi;
    wct_lo[idx] = f2bf(acc - bf2f(hi));
    if (l == 0) whh_hi[g * D + c] = f2bf(w_hh[g * D + c]);
}

// ---------------------------------------------------------------------------
// Fused GRU, LDS-free. Block = 256 thr (4 waves), 64 rows. A-frags loaded
// directly global->reg in MFMA shape (operands stored as bf16 hi/lo).
// 15 MFMA per k-step: (a_hi+a_lo)*wct_hi + a_hi*wct_lo, (h_hi+h_lo)*whh_hi.
#define TM 64
#define MFMA_B16 __builtin_amdgcn_mfma_f32_16x16x32_bf16
__global__ __launch_bounds__(256, 4) void gru_fused_kernel(
    const unsigned short* __restrict__ agg_hi, const unsigned short* __restrict__ agg_lo,
    unsigned short* __restrict__ h_hi, unsigned short* __restrict__ h_lo,
    const unsigned short* __restrict__ wct_hi, const unsigned short* __restrict__ wct_lo,
    const unsigned short* __restrict__ whh_hi,
    const float* __restrict__ b_ih, const float* __restrict__ b_hh) {
    const int tid = threadIdx.x;
    const int lane = tid & 63;
    const int wv = tid >> 6;
    const int fr = lane & 15;  // A row / B col / D col
    const int kg = lane >> 4;  // k-group
    const int m0 = blockIdx.x * TM;

    int arow = m0 + wv * 16 + fr;
    int arc = arow < NN ? arow : NN - 1;
    const long long abase = (long long)arc * D;

    bf16x8 fa_hi[4], fa_lo[4], fh_hi[4], fh_lo[4];
#pragma unroll
    for (int ks = 0; ks < 4; ++ks) {
        int k0 = ks * 32 + kg * 8;
        fa_hi[ks] = *(const bf16x8*)(agg_hi + abase + k0);
        fa_lo[ks] = *(const bf16x8*)(agg_lo + abase + k0);
        fh_hi[ks] = *(const bf16x8*)(h_hi + abase + k0);
        fh_lo[ks] = *(const bf16x8*)(h_lo + abase + k0);
    }

#pragma unroll 1
    for (int dt = 0; dt < 8; ++dt) {
        const int g = dt * 16 + fr;
        f32x4 a_ir = {0, 0, 0, 0}, a_iz = {0, 0, 0, 0}, a_in = {0, 0, 0, 0};
        f32x4 a_hr = {0, 0, 0, 0}, a_hz = {0, 0, 0, 0}, a_hn = {0, 0, 0, 0};
#pragma unroll
        for (int ks = 0; ks < 4; ++ks) {
            int k0 = ks * 32 + kg * 8;
            const long long rR = (long long)(g)*D + k0;
            const long long rZ = (long long)(128 + g) * D + k0;
            const long long rN = (long long)(256 + g) * D + k0;
            bf16x8 birh = *(const bf16x8*)(wct_hi + rR);
            bf16x8 bizh = *(const bf16x8*)(wct_hi + rZ);
            bf16x8 binh = *(const bf16x8*)(wct_hi + rN);
            bf16x8 birl = *(const bf16x8*)(wct_lo + rR);
            bf16x8 bizl = *(const bf16x8*)(wct_lo + rZ);
            bf16x8 binl = *(const bf16x8*)(wct_lo + rN);
            bf16x8 bhr = *(const bf16x8*)(whh_hi + rR);
            bf16x8 bhz = *(const bf16x8*)(whh_hi + rZ);
            bf16x8 bhn = *(const bf16x8*)(whh_hi + rN);
            a_ir = MFMA_B16(fa_hi[ks], birh, a_ir, 0, 0, 0);
            a_ir = MFMA_B16(fa_lo[ks], birh, a_ir, 0, 0, 0);
            a_ir = MFMA_B16(fa_hi[ks], birl, a_ir, 0, 0, 0);
            a_iz = MFMA_B16(fa_hi[ks], bizh, a_iz, 0, 0, 0);
            a_iz = MFMA_B16(fa_lo[ks], bizh, a_iz, 0, 0, 0);
            a_iz = MFMA_B16(fa_hi[ks], bizl, a_iz, 0, 0, 0);
            a_in = MFMA_B16(fa_hi[ks], binh, a_in, 0, 0, 0);
            a_in = MFMA_B16(fa_lo[ks], binh, a_in, 0, 0, 0);
            a_in = MFMA_B16(fa_hi[ks], binl, a_in, 0, 0, 0);
            a_hr = MFMA_B16(fh_hi[ks], bhr, a_hr, 0, 0, 0);
            a_hr = MFMA_B16(fh_lo[ks], bhr, a_hr, 0, 0, 0);
            a_hz = MFMA_B16(fh_hi[ks], bhz, a_hz, 0, 0, 0);
            a_hz = MFMA_B16(fh_lo[ks], bhz, a_hz, 0, 0, 0);
            a_hn = MFMA_B16(fh_hi[ks], bhn, a_hn, 0, 0, 0);
            a_hn = MFMA_B16(fh_lo[ks], bhn, a_hn, 0, 0, 0);
        }
        // Epilogue: C/D layout col = lane&15, row = (lane>>4)*4 + j
        const int d = g;
        float bir = b_ih[d], biz = b_ih[128 + d], bin_ = b_ih[256 + d];
        float bhr_ = b_hh[d], bhz_ = b_hh[128 + d], bhn_ = b_hh[256 + d];
#pragma unroll
        for (int j = 0; j < 4; ++j) {
            int row = m0 + wv * 16 + kg * 4 + j;
            if (row >= NN) continue;
            float ir = a_ir[j] + bir, iz = a_iz[j] + biz, in_ = a_in[j] + bin_;
            float hr = a_hr[j] + bhr_, hz = a_hz[j] + bhz_, hn = a_hn[j] + bhn_;
            float r = 1.f / (1.f + __expf(-(ir + hr)));
            float zz = 1.f / (1.f + __expf(-(iz + hz)));
            float nn = tanhf(in_ + r * hn);
            long long off = (long long)row * D + d;
            float hold = bf2f(h_hi[off]) + bf2f(h_lo[off]);
            float hnew = (1.f - zz) * nn + zz * hold;
            unsigned short nh = f2bf(hnew);
            h_hi[off] = nh;
            h_lo[off] = f2bf(hnew - bf2f(nh));
        }
    }
}

// ---------------------------------------------------------------------------
extern "C" void kernel_launch(void* const* d_in, const int* in_sizes, int n_in,
                              void* d_out, int out_size, void* d_ws, size_t ws_size,
                              hipStream_t stream) {
    const float* z = (const float*)d_in[0];
    const int* ei = (const int*)d_in[1];
    const float* weight = (const float*)d_in[2];
    const float* w_ih = (const float*)d_in[3];
    const float* w_hh = (const float*)d_in[4];
    const float* b_ih = (const float*)d_in[5];
    const float* b_hh = (const float*)d_in[6];
    float* out = (float*)d_out;

    char* ws = (char*)d_ws;
    size_t off = 0;
    unsigned short* wct_hi = (unsigned short*)(ws + off); off += 294912;
    unsigned short* wct_lo = (unsigned short*)(ws + off); off += 294912;
    unsigned short* whh_hi = (unsigned short*)(ws + off); off += 98304;
    int* flag      = (int*)(ws + off); off += 256;
    int* counts    = (int*)(ws + off); off += (size_t)NN * 4;
    int* cursor    = (int*)(ws + off); off += (size_t)NN * 4;
    int* row_start = (int*)(ws + off); off += (size_t)(NN + 16) * 4;
    int* csr_src   = (int*)(ws + off); off += (size_t)NE * 4;
    unsigned short* h_hi = (unsigned short*)(ws + off); off += (size_t)NN * D * 2;
    unsigned short* h_lo = (unsigned short*)(ws + off); off += (size_t)NN * D * 2;
    // agg hi/lo live in d_out (f32 [NN][D] = 2 * bf16 [NN][D]); finalize
    // overwrites d_out only after the last gru has consumed agg.
    unsigned short* agg_hi = (unsigned short*)d_out;
    unsigned short* agg_lo = agg_hi + (size_t)NN * D;

    detect_i64_kernel<<<1, 256, 0, stream>>>(ei, flag);
    hipMemsetAsync(counts, 0, (size_t)NN * 4, stream);
    hist_kernel<<<(NE + 255) / 256, 256, 0, stream>>>(ei, flag, counts);
    scan_kernel<<<1, SCAN_T, 0, stream>>>(counts, row_start, cursor);
    fill_kernel<<<(NE + 255) / 256, 256, 0, stream>>>(ei, flag, cursor, csr_src);
    precompute_weights<<<NL * G3, 128, 0, stream>>>(weight, w_ih, w_hh,
                                                    wct_hi, wct_lo, whh_hi);
    const int npair = NN * D / 2;
    init_h_kernel<<<(npair + 255) / 256, 256, 0, stream>>>(z, h_hi, h_lo);

    for (int l = 0; l < NL; ++l) {
        gather_kernel<<<(NN + 3) / 4, 256, 0, stream>>>(h_hi, h_lo, row_start, csr_src,
                                                        agg_hi, agg_lo);
        long long woff = (long long)l * G3 * D;
        gru_fused_kernel<<<(NN + TM - 1) / TM, 256, 0, stream>>>(
            agg_hi, agg_lo, h_hi, h_lo, wct_hi + woff, wct_lo + woff, whh_hi,
            b_ih, b_hh);
    }
    finalize_kernel<<<(npair + 255) / 256, 256, 0, stream>>>(h_hi, h_lo, out);
}

// Round 5
// 846.653 us; speedup vs baseline: 5.5096x; 1.0466x over previous
//
#include <hip/hip_runtime.h>
#include <hip/hip_bf16.h>

#define NN 50000
#define NE 800000
#define D 128
#define NL 3
#define G3 384

typedef __attribute__((ext_vector_type(4))) float f32x4;
typedef __attribute__((ext_vector_type(2))) float f32x2;
typedef __attribute__((ext_vector_type(8))) __bf16 bf16x8;
typedef unsigned short ushort_t;

static __device__ __forceinline__ unsigned short f2bf(float x) {
    __hip_bfloat16 b = __float2bfloat16(x);
    return *reinterpret_cast<unsigned short*>(&b);
}
static __device__ __forceinline__ float bf2f(unsigned short s) {
    union { unsigned u; float f; } v;
    v.u = ((unsigned)s) << 16;
    return v.f;
}
static __device__ __forceinline__ float lo_of(unsigned u) {
    union { unsigned x; float f; } v;
    v.x = u << 16;
    return v.f;
}
static __device__ __forceinline__ float hi_of(unsigned u) {
    union { unsigned x; float f; } v;
    v.x = u & 0xFFFF0000u;
    return v.f;
}

// ---------------------------------------------------------------------------
__global__ void detect_i64_kernel(const int* __restrict__ ei, int* __restrict__ flag) {
    __shared__ int any_nz;
    if (threadIdx.x == 0) any_nz = 0;
    __syncthreads();
    int v = ei[threadIdx.x * 2 + 1];
    if (v != 0) atomicOr(&any_nz, 1);
    __syncthreads();
    if (threadIdx.x == 0) *flag = (any_nz == 0) ? 1 : 0;  // 1 => int64
}

static __device__ __forceinline__ void load_edge(const int* ei, const int* flag, int e,
                                                 int& src, int& dst) {
    if (*flag) {
        src = ei[2LL * e];
        dst = ei[2LL * (NE + e)];
    } else {
        src = ei[e];
        dst = ei[NE + e];
    }
}

// ---------------------------------------------------------------------------
// CSR build: histogram -> single-block scan -> fill.
__global__ void hist_kernel(const int* __restrict__ ei, const int* __restrict__ flag,
                            int* __restrict__ counts) {
    int e = blockIdx.x * blockDim.x + threadIdx.x;
    if (e >= NE) return;
    int src, dst;
    load_edge(ei, flag, e, src, dst);
    atomicAdd(counts + dst, 1);
}

#define SCAN_T 1024
#define CHUNK 49  // 1024*49 >= 50000
__global__ __launch_bounds__(SCAN_T) void scan_kernel(const int* __restrict__ counts,
                                                      int* __restrict__ row_start,
                                                      int* __restrict__ cursor) {
    __shared__ int lds[SCAN_T];
    const int tid = threadIdx.x;
    const int base = tid * CHUNK;
    int s = 0;
#pragma unroll
    for (int i = 0; i < CHUNK; ++i) {
        int idx = base + i;
        if (idx < NN) s += counts[idx];
    }
    lds[tid] = s;
    __syncthreads();
    for (int off = 1; off < SCAN_T; off <<= 1) {
        int v = (tid >= off) ? lds[tid - off] : 0;
        __syncthreads();
        lds[tid] += v;
        __syncthreads();
    }
    int start = lds[tid] - s;  // exclusive prefix
#pragma unroll
    for (int i = 0; i < CHUNK; ++i) {
        int idx = base + i;
        if (idx < NN) {
            row_start[idx] = start;
            cursor[idx] = start;
            start += counts[idx];
        }
    }
    if (tid == SCAN_T - 1) row_start[NN] = lds[SCAN_T - 1];
}

__global__ void fill_kernel(const int* __restrict__ ei, const int* __restrict__ flag,
                            int* __restrict__ cursor, int* __restrict__ csr_src) {
    int e = blockIdx.x * blockDim.x + threadIdx.x;
    if (e >= NE) return;
    int src, dst;
    load_edge(ei, flag, e, src, dst);
    int slot = atomicAdd(cursor + dst, 1);
    csr_src[slot] = src;
}

// ---------------------------------------------------------------------------
__global__ void init_h_kernel(const float* __restrict__ z,
                              unsigned short* __restrict__ h_hi,
                              unsigned short* __restrict__ h_lo) {
    long long i = (long long)blockIdx.x * blockDim.x + threadIdx.x;
    if (i * 2 >= (long long)NN * D) return;
    f32x2 v = *(const f32x2*)(z + i * 2);
    unsigned short h0 = f2bf(v[0]), h1 = f2bf(v[1]);
    unsigned short l0 = f2bf(v[0] - bf2f(h0)), l1 = f2bf(v[1] - bf2f(h1));
    *(unsigned*)(h_hi + i * 2) = (unsigned)h0 | ((unsigned)h1 << 16);
    *(unsigned*)(h_lo + i * 2) = (unsigned)l0 | ((unsigned)l1 << 16);
}

__global__ void finalize_kernel(const unsigned short* __restrict__ h_hi,
                                const unsigned short* __restrict__ h_lo,
                                float* __restrict__ out) {
    long long i = (long long)blockIdx.x * blockDim.x + threadIdx.x;
    if (i * 2 >= (long long)NN * D) return;
    unsigned uh = *(const unsigned*)(h_hi + i * 2);
    unsigned ul = *(const unsigned*)(h_lo + i * 2);
    f32x2 o;
    o[0] = lo_of(uh) + lo_of(ul);
    o[1] = hi_of(uh) + hi_of(ul);
    *(f32x2*)(out + i * 2) = o;
}

// ---------------------------------------------------------------------------
// Gather: one wave per dst row; agg[dst] = sum h[src]. hi/lo in, hi/lo out.
__global__ __launch_bounds__(256) void gather_kernel(
    const unsigned short* __restrict__ h_hi, const unsigned short* __restrict__ h_lo,
    const int* __restrict__ row_start, const int* __restrict__ csr_src,
    unsigned short* __restrict__ agg_hi, unsigned short* __restrict__ agg_lo) {
    int row = blockIdx.x * 4 + (threadIdx.x >> 6);
    if (row >= NN) return;
    int lane = threadIdx.x & 63;  // covers cols 2*lane, 2*lane+1
    int beg = row_start[row], end = row_start[row + 1];
    float a0 = 0.f, a1 = 0.f, b0 = 0.f, b1 = 0.f;
    int e = beg;
    for (; e + 1 < end; e += 2) {
        int s0 = csr_src[e], s1 = csr_src[e + 1];
        unsigned u0h = *(const unsigned*)(h_hi + (long long)s0 * D + lane * 2);
        unsigned u0l = *(const unsigned*)(h_lo + (long long)s0 * D + lane * 2);
        unsigned u1h = *(const unsigned*)(h_hi + (long long)s1 * D + lane * 2);
        unsigned u1l = *(const unsigned*)(h_lo + (long long)s1 * D + lane * 2);
        a0 += lo_of(u0h) + lo_of(u0l);
        a1 += hi_of(u0h) + hi_of(u0l);
        b0 += lo_of(u1h) + lo_of(u1l);
        b1 += hi_of(u1h) + hi_of(u1l);
    }
    if (e < end) {
        int s0 = csr_src[e];
        unsigned u0h = *(const unsigned*)(h_hi + (long long)s0 * D + lane * 2);
        unsigned u0l = *(const unsigned*)(h_lo + (long long)s0 * D + lane * 2);
        a0 += lo_of(u0h) + lo_of(u0l);
        a1 += hi_of(u0h) + hi_of(u0l);
    }
    float c0 = a0 + b0, c1 = a1 + b1;
    unsigned short h0 = f2bf(c0), h1 = f2bf(c1);
    unsigned short l0 = f2bf(c0 - bf2f(h0)), l1 = f2bf(c1 - bf2f(h1));
    long long off = (long long)row * D + lane * 2;
    *(unsigned*)(agg_hi + off) = (unsigned)h0 | ((unsigned)h1 << 16);
    *(unsigned*)(agg_lo + off) = (unsigned)l0 | ((unsigned)l1 << 16);
}

// ---------------------------------------------------------------------------
__global__ void precompute_weights(const float* __restrict__ weight,
                                   const float* __restrict__ w_ih,
                                   const float* __restrict__ w_hh,
                                   unsigned short* __restrict__ wct_hi,
                                   unsigned short* __restrict__ wct_lo,
                                   unsigned short* __restrict__ whh_hi) {
    int l = blockIdx.x / G3;
    int g = blockIdx.x % G3;
    int c = threadIdx.x;  // 0..127
    __shared__ float wih_row[D];
    wih_row[c] = w_ih[g * D + c];
    __syncthreads();
    const float* wrow = weight + ((long long)l * D + c) * D;
    float acc = 0.f;
#pragma unroll 8
    for (int j = 0; j < D; ++j) acc += wrow[j] * wih_row[j];
    long long idx = ((long long)l * G3 + g) * D + c;
    unsigned short hi = f2bf(acc);
    wct_hi[idx] = hi;
    wct_lo[idx] = f2bf(acc - bf2f(hi));
    if (l == 0) whh_hi[g * D + c] = f2bf(w_hh[g * D + c]);
}

// ---------------------------------------------------------------------------
// Fused GRU, LDS-free. Block = 4 waves x 16 rows = 64 rows, dtpb d-tiles
// starting at blockIdx.y*dtpb. Ping-pong: reads hin, writes hout. When
// hout==hin the launch uses grid.y=1 (full D per block) -> in-place safe.
#define TM 64
#define MFMA_B16 __builtin_amdgcn_mfma_f32_16x16x32_bf16
__global__ __launch_bounds__(256) void gru_fused_kernel(
    const unsigned short* __restrict__ agg_hi, const unsigned short* __restrict__ agg_lo,
    const unsigned short* __restrict__ hin_hi, const unsigned short* __restrict__ hin_lo,
    unsigned short* __restrict__ hout_hi, unsigned short* __restrict__ hout_lo,
    const unsigned short* __restrict__ wct_hi, const unsigned short* __restrict__ wct_lo,
    const unsigned short* __restrict__ whh_hi,
    const float* __restrict__ b_ih, const float* __restrict__ b_hh, int dtpb) {
    const int tid = threadIdx.x;
    const int lane = tid & 63;
    const int wv = tid >> 6;
    const int fr = lane & 15;  // A row / B col / D col
    const int kg = lane >> 4;  // k-group
    const int m0 = blockIdx.x * TM;
    const int dt0 = blockIdx.y * dtpb;

    int arow = m0 + wv * 16 + fr;
    int arc = arow < NN ? arow : NN - 1;
    const int abase = arc * D;  // fits in 32-bit (50000*128 = 6.4M)

    bf16x8 fa_hi[4], fa_lo[4], fh_hi[4], fh_lo[4];
#pragma unroll
    for (int ks = 0; ks < 4; ++ks) {
        int k0 = ks * 32 + kg * 8;
        fa_hi[ks] = *(const bf16x8*)(agg_hi + abase + k0);
        fa_lo[ks] = *(const bf16x8*)(agg_lo + abase + k0);
        fh_hi[ks] = *(const bf16x8*)(hin_hi + abase + k0);
        fh_lo[ks] = *(const bf16x8*)(hin_lo + abase + k0);
    }

#pragma unroll 1
    for (int dti = 0; dti < dtpb; ++dti) {
        const int dt = dt0 + dti;
        const int g = dt * 16 + fr;
        f32x4 a_ir = {0, 0, 0, 0}, a_iz = {0, 0, 0, 0}, a_in = {0, 0, 0, 0};
        f32x4 a_hr = {0, 0, 0, 0}, a_hz = {0, 0, 0, 0}, a_hn = {0, 0, 0, 0};
#pragma unroll
        for (int ks = 0; ks < 4; ++ks) {
            int k0 = ks * 32 + kg * 8;
            const int rR = g * D + k0;
            const int rZ = (128 + g) * D + k0;
            const int rN = (256 + g) * D + k0;
            bf16x8 birh = *(const bf16x8*)(wct_hi + rR);
            bf16x8 bizh = *(const bf16x8*)(wct_hi + rZ);
            bf16x8 binh = *(const bf16x8*)(wct_hi + rN);
            bf16x8 birl = *(const bf16x8*)(wct_lo + rR);
            bf16x8 bizl = *(const bf16x8*)(wct_lo + rZ);
            bf16x8 binl = *(const bf16x8*)(wct_lo + rN);
            bf16x8 bhr = *(const bf16x8*)(whh_hi + rR);
            bf16x8 bhz = *(const bf16x8*)(whh_hi + rZ);
            bf16x8 bhn = *(const bf16x8*)(whh_hi + rN);
            a_ir = MFMA_B16(fa_hi[ks], birh, a_ir, 0, 0, 0);
            a_ir = MFMA_B16(fa_lo[ks], birh, a_ir, 0, 0, 0);
            a_ir = MFMA_B16(fa_hi[ks], birl, a_ir, 0, 0, 0);
            a_iz = MFMA_B16(fa_hi[ks], bizh, a_iz, 0, 0, 0);
            a_iz = MFMA_B16(fa_lo[ks], bizh, a_iz, 0, 0, 0);
            a_iz = MFMA_B16(fa_hi[ks], bizl, a_iz, 0, 0, 0);
            a_in = MFMA_B16(fa_hi[ks], binh, a_in, 0, 0, 0);
            a_in = MFMA_B16(fa_lo[ks], binh, a_in, 0, 0, 0);
            a_in = MFMA_B16(fa_hi[ks], binl, a_in, 0, 0, 0);
            a_hr = MFMA_B16(fh_hi[ks], bhr, a_hr, 0, 0, 0);
            a_hr = MFMA_B16(fh_lo[ks], bhr, a_hr, 0, 0, 0);
            a_hz = MFMA_B16(fh_hi[ks], bhz, a_hz, 0, 0, 0);
            a_hz = MFMA_B16(fh_lo[ks], bhz, a_hz, 0, 0, 0);
            a_hn = MFMA_B16(fh_hi[ks], bhn, a_hn, 0, 0, 0);
            a_hn = MFMA_B16(fh_lo[ks], bhn, a_hn, 0, 0, 0);
        }
        // Epilogue: C/D layout col = lane&15, row = (lane>>4)*4 + j
        const int d = g;
        float bir = b_ih[d], biz = b_ih[128 + d], bin_ = b_ih[256 + d];
        float bhr_ = b_hh[d], bhz_ = b_hh[128 + d], bhn_ = b_hh[256 + d];
#pragma unroll
        for (int j = 0; j < 4; ++j) {
            int row = m0 + wv * 16 + kg * 4 + j;
            if (row >= NN) continue;
            float ir = a_ir[j] + bir, iz = a_iz[j] + biz, in_ = a_in[j] + bin_;
            float hr = a_hr[j] + bhr_, hz = a_hz[j] + bhz_, hn = a_hn[j] + bhn_;
            float r = 1.f / (1.f + __expf(-(ir + hr)));
            float zz = 1.f / (1.f + __expf(-(iz + hz)));
            float nn = tanhf(in_ + r * hn);
            int off = row * D + d;
            float hold = bf2f(hin_hi[off]) + bf2f(hin_lo[off]);
            float hnew = (1.f - zz) * nn + zz * hold;
            unsigned short nh = f2bf(hnew);
            hout_hi[off] = nh;
            hout_lo[off] = f2bf(hnew - bf2f(nh));
        }
    }
}

// ---------------------------------------------------------------------------
extern "C" void kernel_launch(void* const* d_in, const int* in_sizes, int n_in,
                              void* d_out, int out_size, void* d_ws, size_t ws_size,
                              hipStream_t stream) {
    const float* z = (const float*)d_in[0];
    const int* ei = (const int*)d_in[1];
    const float* weight = (const float*)d_in[2];
    const float* w_ih = (const float*)d_in[3];
    const float* w_hh = (const float*)d_in[4];
    const float* b_ih = (const float*)d_in[5];
    const float* b_hh = (const float*)d_in[6];
    float* out = (float*)d_out;

    char* ws = (char*)d_ws;
    size_t off = 0;
    unsigned short* wct_hi = (unsigned short*)(ws + off); off += 294912;
    unsigned short* wct_lo = (unsigned short*)(ws + off); off += 294912;
    unsigned short* whh_hi = (unsigned short*)(ws + off); off += 98304;
    int* flag      = (int*)(ws + off); off += 256;
    int* counts    = (int*)(ws + off); off += (size_t)NN * 4;
    int* cursor    = (int*)(ws + off); off += (size_t)NN * 4;
    int* row_start = (int*)(ws + off); off += (size_t)(NN + 16) * 4;
    int* csr_src   = (int*)(ws + off); off += (size_t)NE * 4;
    unsigned short* hA_hi = (unsigned short*)(ws + off); off += (size_t)NN * D * 2;
    unsigned short* hA_lo = (unsigned short*)(ws + off); off += (size_t)NN * D * 2;
    size_t off_noping = off;
    unsigned short* hB_hi = (unsigned short*)(ws + off); off += (size_t)NN * D * 2;
    unsigned short* hB_lo = (unsigned short*)(ws + off); off += (size_t)NN * D * 2;
    const bool split = (ws_size >= off);  // room for ping-pong buffers?
    if (!split) { hB_hi = hA_hi; hB_lo = hA_lo; (void)off_noping; }

    // agg hi/lo live in d_out (f32 [NN][D] = 2 * bf16 [NN][D]); finalize
    // overwrites d_out only after the last gru has consumed agg.
    unsigned short* agg_hi = (unsigned short*)d_out;
    unsigned short* agg_lo = agg_hi + (size_t)NN * D;

    detect_i64_kernel<<<1, 256, 0, stream>>>(ei, flag);
    hipMemsetAsync(counts, 0, (size_t)NN * 4, stream);
    hist_kernel<<<(NE + 255) / 256, 256, 0, stream>>>(ei, flag, counts);
    scan_kernel<<<1, SCAN_T, 0, stream>>>(counts, row_start, cursor);
    fill_kernel<<<(NE + 255) / 256, 256, 0, stream>>>(ei, flag, cursor, csr_src);
    precompute_weights<<<NL * G3, 128, 0, stream>>>(weight, w_ih, w_hh,
                                                    wct_hi, wct_lo, whh_hi);
    const int npair = NN * D / 2;
    init_h_kernel<<<(npair + 255) / 256, 256, 0, stream>>>(z, hA_hi, hA_lo);

    const int dtpb = split ? 4 : 8;
    const dim3 gg((NN + TM - 1) / TM, split ? 2 : 1);
    const unsigned short* cin_hi = hA_hi;
    const unsigned short* cin_lo = hA_lo;
    for (int l = 0; l < NL; ++l) {
        gather_kernel<<<(NN + 3) / 4, 256, 0, stream>>>(cin_hi, cin_lo, row_start,
                                                        csr_src, agg_hi, agg_lo);
        unsigned short* cout_hi;
        unsigned short* cout_lo;
        if (split) {
            cout_hi = (cin_hi == hA_hi) ? hB_hi : hA_hi;
            cout_lo = (cin_lo == hA_lo) ? hB_lo : hA_lo;
        } else {
            cout_hi = (unsigned short*)cin_hi;
            cout_lo = (unsigned short*)cin_lo;
        }
        long long woff = (long long)l * G3 * D;
        gru_fused_kernel<<<gg, 256, 0, stream>>>(
            agg_hi, agg_lo, cin_hi, cin_lo, cout_hi, cout_lo,
            wct_hi + woff, wct_lo + woff, whh_hi, b_ih, b_hh, dtpb);
        cin_hi = cout_hi;
        cin_lo = cout_lo;
    }
    finalize_kernel<<<(npair + 255) / 256, 256, 0, stream>>>(cin_hi, cin_lo, out);
}

// Round 6
// 624.244 us; speedup vs baseline: 7.4726x; 1.3563x over previous
//
#include <hip/hip_runtime.h>
#include <hip/hip_bf16.h>

#define NN 50000
#define NE 800000
#define D 128
#define NL 3
#define G3 384

typedef __attribute__((ext_vector_type(4))) float f32x4;
typedef __attribute__((ext_vector_type(2))) float f32x2;
typedef _Float16 f16;
typedef __attribute__((ext_vector_type(8))) _Float16 f16x8;
typedef __attribute__((ext_vector_type(2))) _Float16 f16x2;

// ---------------------------------------------------------------------------
__global__ void detect_i64_kernel(const int* __restrict__ ei, int* __restrict__ flag) {
    __shared__ int any_nz;
    if (threadIdx.x == 0) any_nz = 0;
    __syncthreads();
    int v = ei[threadIdx.x * 2 + 1];
    if (v != 0) atomicOr(&any_nz, 1);
    __syncthreads();
    if (threadIdx.x == 0) *flag = (any_nz == 0) ? 1 : 0;  // 1 => int64
}

static __device__ __forceinline__ void load_edge(const int* ei, const int* flag, int e,
                                                 int& src, int& dst) {
    if (*flag) {
        src = ei[2LL * e];
        dst = ei[2LL * (NE + e)];
    } else {
        src = ei[e];
        dst = ei[NE + e];
    }
}

// ---------------------------------------------------------------------------
// CSR build: histogram -> single-block scan -> fill.
__global__ void hist_kernel(const int* __restrict__ ei, const int* __restrict__ flag,
                            int* __restrict__ counts) {
    int e = blockIdx.x * blockDim.x + threadIdx.x;
    if (e >= NE) return;
    int src, dst;
    load_edge(ei, flag, e, src, dst);
    atomicAdd(counts + dst, 1);
}

#define SCAN_T 1024
#define CHUNK 49  // 1024*49 >= 50000
__global__ __launch_bounds__(SCAN_T) void scan_kernel(const int* __restrict__ counts,
                                                      int* __restrict__ row_start,
                                                      int* __restrict__ cursor) {
    __shared__ int lds[SCAN_T];
    const int tid = threadIdx.x;
    const int base = tid * CHUNK;
    int s = 0;
#pragma unroll
    for (int i = 0; i < CHUNK; ++i) {
        int idx = base + i;
        if (idx < NN) s += counts[idx];
    }
    lds[tid] = s;
    __syncthreads();
    for (int off = 1; off < SCAN_T; off <<= 1) {
        int v = (tid >= off) ? lds[tid - off] : 0;
        __syncthreads();
        lds[tid] += v;
        __syncthreads();
    }
    int start = lds[tid] - s;  // exclusive prefix
#pragma unroll
    for (int i = 0; i < CHUNK; ++i) {
        int idx = base + i;
        if (idx < NN) {
            row_start[idx] = start;
            cursor[idx] = start;
            start += counts[idx];
        }
    }
    if (tid == SCAN_T - 1) row_start[NN] = lds[SCAN_T - 1];
}

__global__ void fill_kernel(const int* __restrict__ ei, const int* __restrict__ flag,
                            int* __restrict__ cursor, int* __restrict__ csr_src) {
    int e = blockIdx.x * blockDim.x + threadIdx.x;
    if (e >= NE) return;
    int src, dst;
    load_edge(ei, flag, e, src, dst);
    int slot = atomicAdd(cursor + dst, 1);
    csr_src[slot] = src;
}

// ---------------------------------------------------------------------------
__global__ void init_h_kernel(const float* __restrict__ z, f16* __restrict__ h) {
    int i = blockIdx.x * blockDim.x + threadIdx.x;
    if (i * 2 >= NN * D) return;
    f32x2 v = *(const f32x2*)(z + i * 2);
    f16x2 o = {(f16)v[0], (f16)v[1]};
    *(f16x2*)(h + i * 2) = o;
}

__global__ void finalize_kernel(const f16* __restrict__ h, float* __restrict__ out) {
    int i = blockIdx.x * blockDim.x + threadIdx.x;
    if (i * 2 >= NN * D) return;
    f16x2 v = *(const f16x2*)(h + i * 2);
    f32x2 o = {(float)v[0], (float)v[1]};
    *(f32x2*)(out + i * 2) = o;
}

// ---------------------------------------------------------------------------
// Gather: one wave per dst row; agg[dst] = sum h[src] (f32 accum, f16 out).
// 4-edge unroll for MLP; each lane covers cols 2*lane, 2*lane+1 (4B loads).
__global__ __launch_bounds__(256) void gather_kernel(
    const f16* __restrict__ h, const int* __restrict__ row_start,
    const int* __restrict__ csr_src, f16* __restrict__ agg) {
    int row = blockIdx.x * 4 + (threadIdx.x >> 6);
    if (row >= NN) return;
    int lane = threadIdx.x & 63;
    int beg = row_start[row], end = row_start[row + 1];
    float a0 = 0.f, a1 = 0.f, b0 = 0.f, b1 = 0.f;
    float c0 = 0.f, c1 = 0.f, d0 = 0.f, d1 = 0.f;
    int e = beg;
    for (; e + 3 < end; e += 4) {
        int s0 = csr_src[e], s1 = csr_src[e + 1], s2 = csr_src[e + 2], s3 = csr_src[e + 3];
        f16x2 v0 = *(const f16x2*)(h + s0 * D + lane * 2);
        f16x2 v1 = *(const f16x2*)(h + s1 * D + lane * 2);
        f16x2 v2 = *(const f16x2*)(h + s2 * D + lane * 2);
        f16x2 v3 = *(const f16x2*)(h + s3 * D + lane * 2);
        a0 += (float)v0[0]; a1 += (float)v0[1];
        b0 += (float)v1[0]; b1 += (float)v1[1];
        c0 += (float)v2[0]; c1 += (float)v2[1];
        d0 += (float)v3[0]; d1 += (float)v3[1];
    }
    for (; e < end; ++e) {
        int s0 = csr_src[e];
        f16x2 v0 = *(const f16x2*)(h + s0 * D + lane * 2);
        a0 += (float)v0[0]; a1 += (float)v0[1];
    }
    float s0f = (a0 + b0) + (c0 + d0);
    float s1f = (a1 + b1) + (c1 + d1);
    f16x2 o = {(f16)s0f, (f16)s1f};
    *(f16x2*)(agg + row * D + lane * 2) = o;
}

// ---------------------------------------------------------------------------
// WcT[l][g][c] = sum_j weight[l][c][j] * w_ih[g][j] (fp16); whh fp16.
__global__ void precompute_weights(const float* __restrict__ weight,
                                   const float* __restrict__ w_ih,
                                   const float* __restrict__ w_hh,
                                   f16* __restrict__ wct, f16* __restrict__ whh) {
    int l = blockIdx.x / G3;
    int g = blockIdx.x % G3;
    int c = threadIdx.x;  // 0..127
    __shared__ float wih_row[D];
    wih_row[c] = w_ih[g * D + c];
    __syncthreads();
    const float* wrow = weight + ((long long)l * D + c) * D;
    float acc = 0.f;
#pragma unroll 8
    for (int j = 0; j < D; ++j) acc += wrow[j] * wih_row[j];
    wct[((long long)l * G3 + g) * D + c] = (f16)acc;
    if (l == 0) whh[g * D + c] = (f16)w_hh[g * D + c];
}

// ---------------------------------------------------------------------------
// Fused GRU, LDS-free, fp16 operands. Block = 4 waves x 16 rows, dtpb d-tiles
// at blockIdx.y*dtpb. Ping-pong: reads hin, writes hout (in-place only when
// grid.y==1). 6 MFMA + 6 weight loads per k-step.
#define TM 64
#define MFMA_F16 __builtin_amdgcn_mfma_f32_16x16x32_f16
__global__ __launch_bounds__(256) void gru_fused_kernel(
    const f16* __restrict__ agg, const f16* __restrict__ hin, f16* __restrict__ hout,
    const f16* __restrict__ wct, const f16* __restrict__ whh,
    const float* __restrict__ b_ih, const float* __restrict__ b_hh, int dtpb) {
    const int tid = threadIdx.x;
    const int lane = tid & 63;
    const int wv = tid >> 6;
    const int fr = lane & 15;  // A row / B col / D col
    const int kg = lane >> 4;  // k-group
    const int m0 = blockIdx.x * TM;
    const int dt0 = blockIdx.y * dtpb;

    int arow = m0 + wv * 16 + fr;
    int arc = arow < NN ? arow : NN - 1;
    const int abase = arc * D;

    f16x8 fa[4], fh[4];
#pragma unroll
    for (int ks = 0; ks < 4; ++ks) {
        int k0 = ks * 32 + kg * 8;
        fa[ks] = *(const f16x8*)(agg + abase + k0);
        fh[ks] = *(const f16x8*)(hin + abase + k0);
    }

#pragma unroll 1
    for (int dti = 0; dti < dtpb; ++dti) {
        const int dt = dt0 + dti;
        const int g = dt * 16 + fr;
        f32x4 a_ir = {0, 0, 0, 0}, a_iz = {0, 0, 0, 0}, a_in = {0, 0, 0, 0};
        f32x4 a_hr = {0, 0, 0, 0}, a_hz = {0, 0, 0, 0}, a_hn = {0, 0, 0, 0};
#pragma unroll
        for (int ks = 0; ks < 4; ++ks) {
            int k0 = ks * 32 + kg * 8;
            const int rR = g * D + k0;
            const int rZ = (128 + g) * D + k0;
            const int rN = (256 + g) * D + k0;
            f16x8 bir = *(const f16x8*)(wct + rR);
            f16x8 biz = *(const f16x8*)(wct + rZ);
            f16x8 bin = *(const f16x8*)(wct + rN);
            f16x8 bhr = *(const f16x8*)(whh + rR);
            f16x8 bhz = *(const f16x8*)(whh + rZ);
            f16x8 bhn = *(const f16x8*)(whh + rN);
            a_ir = MFMA_F16(fa[ks], bir, a_ir, 0, 0, 0);
            a_iz = MFMA_F16(fa[ks], biz, a_iz, 0, 0, 0);
            a_in = MFMA_F16(fa[ks], bin, a_in, 0, 0, 0);
            a_hr = MFMA_F16(fh[ks], bhr, a_hr, 0, 0, 0);
            a_hz = MFMA_F16(fh[ks], bhz, a_hz, 0, 0, 0);
            a_hn = MFMA_F16(fh[ks], bhn, a_hn, 0, 0, 0);
        }
        // Epilogue: C/D layout col = lane&15, row = (lane>>4)*4 + j
        const int d = g;
        float bir_ = b_ih[d], biz_ = b_ih[128 + d], bin_ = b_ih[256 + d];
        float bhr_ = b_hh[d], bhz_ = b_hh[128 + d], bhn_ = b_hh[256 + d];
#pragma unroll
        for (int j = 0; j < 4; ++j) {
            int row = m0 + wv * 16 + kg * 4 + j;
            if (row >= NN) continue;
            float ir = a_ir[j] + bir_, iz = a_iz[j] + biz_, in_ = a_in[j] + bin_;
            float hr = a_hr[j] + bhr_, hz = a_hz[j] + bhz_, hn = a_hn[j] + bhn_;
            float r = 1.f / (1.f + __expf(-(ir + hr)));
            float zz = 1.f / (1.f + __expf(-(iz + hz)));
            float nn = tanhf(in_ + r * hn);
            int off = row * D + d;
            float hold = (float)hin[off];
            float hnew = (1.f - zz) * nn + zz * hold;
            hout[off] = (f16)hnew;
        }
    }
}

// ---------------------------------------------------------------------------
extern "C" void kernel_launch(void* const* d_in, const int* in_sizes, int n_in,
                              void* d_out, int out_size, void* d_ws, size_t ws_size,
                              hipStream_t stream) {
    const float* z = (const float*)d_in[0];
    const int* ei = (const int*)d_in[1];
    const float* weight = (const float*)d_in[2];
    const float* w_ih = (const float*)d_in[3];
    const float* w_hh = (const float*)d_in[4];
    const float* b_ih = (const float*)d_in[5];
    const float* b_hh = (const float*)d_in[6];
    float* out = (float*)d_out;

    char* ws = (char*)d_ws;
    size_t off = 0;
    f16* wct = (f16*)(ws + off); off += 294912;
    f16* whh = (f16*)(ws + off); off += 98304;
    int* flag      = (int*)(ws + off); off += 256;
    int* counts    = (int*)(ws + off); off += (size_t)NN * 4;
    int* cursor    = (int*)(ws + off); off += (size_t)NN * 4;
    int* row_start = (int*)(ws + off); off += (size_t)(NN + 16) * 4;
    int* csr_src   = (int*)(ws + off); off += (size_t)NE * 4;
    f16* agg  = (f16*)(ws + off); off += (size_t)NN * D * 2;
    f16* hA   = (f16*)(ws + off); off += (size_t)NN * D * 2;
    size_t off_min = off;
    f16* hB   = (f16*)(ws + off); off += (size_t)NN * D * 2;
    const bool split = (ws_size >= off);  // room for ping-pong buffer?
    if (!split) { hB = hA; (void)off_min; }

    detect_i64_kernel<<<1, 256, 0, stream>>>(ei, flag);
    hipMemsetAsync(counts, 0, (size_t)NN * 4, stream);
    hist_kernel<<<(NE + 255) / 256, 256, 0, stream>>>(ei, flag, counts);
    scan_kernel<<<1, SCAN_T, 0, stream>>>(counts, row_start, cursor);
    fill_kernel<<<(NE + 255) / 256, 256, 0, stream>>>(ei, flag, cursor, csr_src);
    precompute_weights<<<NL * G3, 128, 0, stream>>>(weight, w_ih, w_hh, wct, whh);
    const int npair = NN * D / 2;
    init_h_kernel<<<(npair + 255) / 256, 256, 0, stream>>>(z, hA);

    const int dtpb = split ? 4 : 8;
    const dim3 gg((NN + TM - 1) / TM, split ? 2 : 1);
    const f16* cin = hA;
    for (int l = 0; l < NL; ++l) {
        gather_kernel<<<(NN + 3) / 4, 256, 0, stream>>>(cin, row_start, csr_src, agg);
        f16* cout = split ? ((cin == hA) ? hB : hA) : (f16*)cin;
        long long woff = (long long)l * G3 * D;
        gru_fused_kernel<<<gg, 256, 0, stream>>>(agg, cin, cout, wct + woff, whh,
                                                 b_ih, b_hh, dtpb);
        cin = cout;
    }
    finalize_kernel<<<(npair + 255) / 256, 256, 0, stream>>>(cin, out);
}

// Round 7
// 521.141 us; speedup vs baseline: 8.9510x; 1.1978x over previous
//
#include <hip/hip_runtime.h>
#include <hip/hip_bf16.h>

#define NN 50000
#define NE 800000
#define D 128
#define NL 3
#define G3 384

typedef __attribute__((ext_vector_type(4))) float f32x4;
typedef __attribute__((ext_vector_type(2))) float f32x2;
typedef _Float16 f16;
typedef __attribute__((ext_vector_type(8))) _Float16 f16x8;
typedef __attribute__((ext_vector_type(2))) _Float16 f16x2;

// ---------------------------------------------------------------------------
__global__ void detect_i64_kernel(const int* __restrict__ ei, int* __restrict__ flag) {
    __shared__ int any_nz;
    if (threadIdx.x == 0) any_nz = 0;
    __syncthreads();
    int v = ei[threadIdx.x * 2 + 1];
    if (v != 0) atomicOr(&any_nz, 1);
    __syncthreads();
    if (threadIdx.x == 0) *flag = (any_nz == 0) ? 1 : 0;  // 1 => int64
}

static __device__ __forceinline__ void load_edge(const int* ei, const int* flag, int e,
                                                 int& src, int& dst) {
    if (*flag) {
        src = ei[2LL * e];
        dst = ei[2LL * (NE + e)];
    } else {
        src = ei[e];
        dst = ei[NE + e];
    }
}

// ---------------------------------------------------------------------------
// CSR build: histogram -> parallel 3-phase scan -> fill.
__global__ void hist_kernel(const int* __restrict__ ei, const int* __restrict__ flag,
                            int* __restrict__ counts) {
    int e = blockIdx.x * blockDim.x + threadIdx.x;
    if (e >= NE) return;
    int src, dst;
    load_edge(ei, flag, e, src, dst);
    atomicAdd(counts + dst, 1);
}

#define SBLK 256
#define NSB ((NN + SBLK - 1) / SBLK)  // 196

__global__ __launch_bounds__(SBLK) void scan_reduce_kernel(const int* __restrict__ counts,
                                                           int* __restrict__ block_sums) {
    __shared__ int lds[SBLK];
    int i = blockIdx.x * SBLK + threadIdx.x;
    lds[threadIdx.x] = (i < NN) ? counts[i] : 0;
    __syncthreads();
    for (int off = SBLK / 2; off > 0; off >>= 1) {
        if (threadIdx.x < off) lds[threadIdx.x] += lds[threadIdx.x + off];
        __syncthreads();
    }
    if (threadIdx.x == 0) block_sums[blockIdx.x] = lds[0];
}

__global__ __launch_bounds__(256) void scan_offsets_kernel(const int* __restrict__ block_sums,
                                                           int* __restrict__ block_off,
                                                           int* __restrict__ row_start) {
    __shared__ int lds[256];
    int t = threadIdx.x;
    int v = (t < NSB) ? block_sums[t] : 0;
    lds[t] = v;
    __syncthreads();
    for (int off = 1; off < 256; off <<= 1) {
        int x = (t >= off) ? lds[t - off] : 0;
        __syncthreads();
        lds[t] += x;
        __syncthreads();
    }
    if (t < NSB) block_off[t] = lds[t] - v;  // exclusive
    if (t == 255) row_start[NN] = lds[255];  // total = NE
}

__global__ __launch_bounds__(SBLK) void scan_final_kernel(const int* __restrict__ counts,
                                                          const int* __restrict__ block_off,
                                                          int* __restrict__ row_start,
                                                          int* __restrict__ cursor) {
    __shared__ int lds[SBLK];
    int i = blockIdx.x * SBLK + threadIdx.x;
    int v = (i < NN) ? counts[i] : 0;
    lds[threadIdx.x] = v;
    __syncthreads();
    for (int off = 1; off < SBLK; off <<= 1) {
        int x = (threadIdx.x >= off) ? lds[threadIdx.x - off] : 0;
        __syncthreads();
        lds[threadIdx.x] += x;
        __syncthreads();
    }
    if (i < NN) {
        int excl = block_off[blockIdx.x] + lds[threadIdx.x] - v;
        row_start[i] = excl;
        cursor[i] = excl;
    }
}

__global__ void fill_kernel(const int* __restrict__ ei, const int* __restrict__ flag,
                            int* __restrict__ cursor, int* __restrict__ csr_src) {
    int e = blockIdx.x * blockDim.x + threadIdx.x;
    if (e >= NE) return;
    int src, dst;
    load_edge(ei, flag, e, src, dst);
    int slot = atomicAdd(cursor + dst, 1);
    csr_src[slot] = src;
}

// ---------------------------------------------------------------------------
__global__ void init_h_kernel(const float* __restrict__ z, f16* __restrict__ h) {
    int i = blockIdx.x * blockDim.x + threadIdx.x;
    if (i * 2 >= NN * D) return;
    f32x2 v = *(const f32x2*)(z + i * 2);
    f16x2 o = {(f16)v[0], (f16)v[1]};
    *(f16x2*)(h + i * 2) = o;
}

__global__ void finalize_kernel(const f16* __restrict__ h, float* __restrict__ out) {
    int i = blockIdx.x * blockDim.x + threadIdx.x;
    if (i * 2 >= NN * D) return;
    f16x2 v = *(const f16x2*)(h + i * 2);
    f32x2 o = {(float)v[0], (float)v[1]};
    *(f32x2*)(out + i * 2) = o;
}

// ---------------------------------------------------------------------------
// Gather: one wave per dst row. Lanes split 4 (edge slots) x 16 (row chunk):
// each lane loads f16x8 (16B); 16 lanes cover one 256B row; 4 edges/iter.
// Final cross-slot reduce via shfl_xor(16/32); lanes 0-15 write the row.
__global__ __launch_bounds__(256) void gather_kernel(
    const f16* __restrict__ h, const int* __restrict__ row_start,
    const int* __restrict__ csr_src, f16* __restrict__ agg) {
    int row = blockIdx.x * 4 + (threadIdx.x >> 6);
    if (row >= NN) return;
    int lane = threadIdx.x & 63;
    int eslot = lane >> 4;       // 0..3
    int c0 = (lane & 15) * 8;    // col base (8 f16 = 16 B)
    int beg = row_start[row], end = row_start[row + 1];
    float acc[8] = {0.f, 0.f, 0.f, 0.f, 0.f, 0.f, 0.f, 0.f};
    for (int base = beg; base + eslot < end; base += 4) {
        int s = csr_src[base + eslot];
        f16x8 v = *(const f16x8*)(h + s * D + c0);
#pragma unroll
        for (int j = 0; j < 8; ++j) acc[j] += (float)v[j];
    }
#pragma unroll
    for (int j = 0; j < 8; ++j) {
        acc[j] += __shfl_xor(acc[j], 16, 64);
        acc[j] += __shfl_xor(acc[j], 32, 64);
    }
    if (lane < 16) {
        f16x8 o;
#pragma unroll
        for (int j = 0; j < 8; ++j) o[j] = (f16)acc[j];
        *(f16x8*)(agg + row * D + c0) = o;
    }
}

// ---------------------------------------------------------------------------
// WcT[l][g][c] = sum_j weight[l][c][j] * w_ih[g][j] (fp16); whh fp16.
__global__ void precompute_weights(const float* __restrict__ weight,
                                   const float* __restrict__ w_ih,
                                   const float* __restrict__ w_hh,
                                   f16* __restrict__ wct, f16* __restrict__ whh) {
    int l = blockIdx.x / G3;
    int g = blockIdx.x % G3;
    int c = threadIdx.x;  // 0..127
    __shared__ float wih_row[D];
    wih_row[c] = w_ih[g * D + c];
    __syncthreads();
    const float* wrow = weight + ((long long)l * D + c) * D;
    float acc = 0.f;
#pragma unroll 8
    for (int j = 0; j < D; ++j) acc += wrow[j] * wih_row[j];
    wct[((long long)l * G3 + g) * D + c] = (f16)acc;
    if (l == 0) whh[g * D + c] = (f16)w_hh[g * D + c];
}

// ---------------------------------------------------------------------------
// Fused GRU, LDS-free, fp16 operands. Block = 4 waves x 16 rows, dtpb d-tiles
// at blockIdx.y*dtpb. Ping-pong: reads hin, writes hout (in-place only when
// grid.y==1). 6 MFMA + 6 weight loads per k-step.
#define TM 64
#define MFMA_F16 __builtin_amdgcn_mfma_f32_16x16x32_f16
__global__ __launch_bounds__(256) void gru_fused_kernel(
    const f16* __restrict__ agg, const f16* __restrict__ hin, f16* __restrict__ hout,
    const f16* __restrict__ wct, const f16* __restrict__ whh,
    const float* __restrict__ b_ih, const float* __restrict__ b_hh, int dtpb) {
    const int tid = threadIdx.x;
    const int lane = tid & 63;
    const int wv = tid >> 6;
    const int fr = lane & 15;  // A row / B col / D col
    const int kg = lane >> 4;  // k-group
    const int m0 = blockIdx.x * TM;
    const int dt0 = blockIdx.y * dtpb;

    int arow = m0 + wv * 16 + fr;
    int arc = arow < NN ? arow : NN - 1;
    const int abase = arc * D;

    f16x8 fa[4], fh[4];
#pragma unroll
    for (int ks = 0; ks < 4; ++ks) {
        int k0 = ks * 32 + kg * 8;
        fa[ks] = *(const f16x8*)(agg + abase + k0);
        fh[ks] = *(const f16x8*)(hin + abase + k0);
    }

#pragma unroll 1
    for (int dti = 0; dti < dtpb; ++dti) {
        const int dt = dt0 + dti;
        const int g = dt * 16 + fr;
        f32x4 a_ir = {0, 0, 0, 0}, a_iz = {0, 0, 0, 0}, a_in = {0, 0, 0, 0};
        f32x4 a_hr = {0, 0, 0, 0}, a_hz = {0, 0, 0, 0}, a_hn = {0, 0, 0, 0};
#pragma unroll
        for (int ks = 0; ks < 4; ++ks) {
            int k0 = ks * 32 + kg * 8;
            const int rR = g * D + k0;
            const int rZ = (128 + g) * D + k0;
            const int rN = (256 + g) * D + k0;
            f16x8 bir = *(const f16x8*)(wct + rR);
            f16x8 biz = *(const f16x8*)(wct + rZ);
            f16x8 bin = *(const f16x8*)(wct + rN);
            f16x8 bhr = *(const f16x8*)(whh + rR);
            f16x8 bhz = *(const f16x8*)(whh + rZ);
            f16x8 bhn = *(const f16x8*)(whh + rN);
            a_ir = MFMA_F16(fa[ks], bir, a_ir, 0, 0, 0);
            a_iz = MFMA_F16(fa[ks], biz, a_iz, 0, 0, 0);
            a_in = MFMA_F16(fa[ks], bin, a_in, 0, 0, 0);
            a_hr = MFMA_F16(fh[ks], bhr, a_hr, 0, 0, 0);
            a_hz = MFMA_F16(fh[ks], bhz, a_hz, 0, 0, 0);
            a_hn = MFMA_F16(fh[ks], bhn, a_hn, 0, 0, 0);
        }
        // Epilogue: C/D layout col = lane&15, row = (lane>>4)*4 + j
        const int d = g;
        float bir_ = b_ih[d], biz_ = b_ih[128 + d], bin_ = b_ih[256 + d];
        float bhr_ = b_hh[d], bhz_ = b_hh[128 + d], bhn_ = b_hh[256 + d];
#pragma unroll
        for (int j = 0; j < 4; ++j) {
            int row = m0 + wv * 16 + kg * 4 + j;
            if (row >= NN) continue;
            float ir = a_ir[j] + bir_, iz = a_iz[j] + biz_, in_ = a_in[j] + bin_;
            float hr = a_hr[j] + bhr_, hz = a_hz[j] + bhz_, hn = a_hn[j] + bhn_;
            float r = 1.f / (1.f + __expf(-(ir + hr)));
            float zz = 1.f / (1.f + __expf(-(iz + hz)));
            float nn = tanhf(in_ + r * hn);
            int off = row * D + d;
            float hold = (float)hin[off];
            float hnew = (1.f - zz) * nn + zz * hold;
            hout[off] = (f16)hnew;
        }
    }
}

// ---------------------------------------------------------------------------
extern "C" void kernel_launch(void* const* d_in, const int* in_sizes, int n_in,
                              void* d_out, int out_size, void* d_ws, size_t ws_size,
                              hipStream_t stream) {
    const float* z = (const float*)d_in[0];
    const int* ei = (const int*)d_in[1];
    const float* weight = (const float*)d_in[2];
    const float* w_ih = (const float*)d_in[3];
    const float* w_hh = (const float*)d_in[4];
    const float* b_ih = (const float*)d_in[5];
    const float* b_hh = (const float*)d_in[6];
    float* out = (float*)d_out;

    char* ws = (char*)d_ws;
    size_t off = 0;
    f16* wct = (f16*)(ws + off); off += 294912;
    f16* whh = (f16*)(ws + off); off += 98304;
    int* flag       = (int*)(ws + off); off += 256;
    int* counts     = (int*)(ws + off); off += (size_t)NN * 4;
    int* cursor     = (int*)(ws + off); off += (size_t)NN * 4;
    int* row_start  = (int*)(ws + off); off += (size_t)(NN + 16) * 4;
    int* block_sums = (int*)(ws + off); off += (size_t)NSB * 4;
    int* block_off  = (int*)(ws + off); off += (size_t)NSB * 4;
    int* csr_src    = (int*)(ws + off); off += (size_t)NE * 4;
    f16* agg  = (f16*)(ws + off); off += (size_t)NN * D * 2;
    f16* hA   = (f16*)(ws + off); off += (size_t)NN * D * 2;
    size_t off_min = off;
    f16* hB   = (f16*)(ws + off); off += (size_t)NN * D * 2;
    const bool split = (ws_size >= off);  // room for ping-pong buffer?
    if (!split) { hB = hA; (void)off_min; }

    detect_i64_kernel<<<1, 256, 0, stream>>>(ei, flag);
    hipMemsetAsync(counts, 0, (size_t)NN * 4, stream);
    hist_kernel<<<(NE + 255) / 256, 256, 0, stream>>>(ei, flag, counts);
    scan_reduce_kernel<<<NSB, SBLK, 0, stream>>>(counts, block_sums);
    scan_offsets_kernel<<<1, 256, 0, stream>>>(block_sums, block_off, row_start);
    scan_final_kernel<<<NSB, SBLK, 0, stream>>>(counts, block_off, row_start, cursor);
    fill_kernel<<<(NE + 255) / 256, 256, 0, stream>>>(ei, flag, cursor, csr_src);
    precompute_weights<<<NL * G3, 128, 0, stream>>>(weight, w_ih, w_hh, wct, whh);
    const int npair = NN * D / 2;
    init_h_kernel<<<(npair + 255) / 256, 256, 0, stream>>>(z, hA);

    const int dtpb = split ? 2 : 8;
    const dim3 gg((NN + TM - 1) / TM, split ? 4 : 1);
    const f16* cin = hA;
    for (int l = 0; l < NL; ++l) {
        gather_kernel<<<(NN + 3) / 4, 256, 0, stream>>>(cin, row_start, csr_src, agg);
        f16* cout = split ? ((cin == hA) ? hB : hA) : (f16*)cin;
        long long woff = (long long)l * G3 * D;
        gru_fused_kernel<<<gg, 256, 0, stream>>>(agg, cin, cout, wct + woff, whh,
                                                 b_ih, b_hh, dtpb);
        cin = cout;
    }
    finalize_kernel<<<(npair + 255) / 256, 256, 0, stream>>>(cin, out);
}

// Round 9
// 375.139 us; speedup vs baseline: 12.4347x; 1.3892x over previous
//
#include <hip/hip_runtime.h>
#include <hip/hip_bf16.h>

#define NN 50000
#define NE 800000
#define D 128
#define NL 3
#define G3 384

typedef __attribute__((ext_vector_type(4))) float f32x4;
typedef __attribute__((ext_vector_type(2))) float f32x2;
typedef _Float16 f16;
typedef __attribute__((ext_vector_type(8))) _Float16 f16x8;
typedef __attribute__((ext_vector_type(2))) _Float16 f16x2;

// ---------------------------------------------------------------------------
__global__ void detect_i64_kernel(const int* __restrict__ ei, int* __restrict__ flag) {
    __shared__ int any_nz;
    if (threadIdx.x == 0) any_nz = 0;
    __syncthreads();
    int v = ei[threadIdx.x * 2 + 1];
    if (v != 0) atomicOr(&any_nz, 1);
    __syncthreads();
    if (threadIdx.x == 0) *flag = (any_nz == 0) ? 1 : 0;  // 1 => int64
}

static __device__ __forceinline__ void load_edge(const int* ei, const int* flag, int e,
                                                 int& src, int& dst) {
    if (*flag) {
        src = ei[2LL * e];
        dst = ei[2LL * (NE + e)];
    } else {
        src = ei[e];
        dst = ei[NE + e];
    }
}

// ---------------------------------------------------------------------------
// CSR build: histogram -> parallel 3-phase scan -> fill.
__global__ void hist_kernel(const int* __restrict__ ei, const int* __restrict__ flag,
                            int* __restrict__ counts) {
    int e = blockIdx.x * blockDim.x + threadIdx.x;
    if (e >= NE) return;
    int src, dst;
    load_edge(ei, flag, e, src, dst);
    atomicAdd(counts + dst, 1);
}

#define SBLK 256
#define NSB ((NN + SBLK - 1) / SBLK)  // 196

__global__ __launch_bounds__(SBLK) void scan_reduce_kernel(const int* __restrict__ counts,
                                                           int* __restrict__ block_sums) {
    __shared__ int lds[SBLK];
    int i = blockIdx.x * SBLK + threadIdx.x;
    lds[threadIdx.x] = (i < NN) ? counts[i] : 0;
    __syncthreads();
    for (int off = SBLK / 2; off > 0; off >>= 1) {
        if (threadIdx.x < off) lds[threadIdx.x] += lds[threadIdx.x + off];
        __syncthreads();
    }
    if (threadIdx.x == 0) block_sums[blockIdx.x] = lds[0];
}

__global__ __launch_bounds__(256) void scan_offsets_kernel(const int* __restrict__ block_sums,
                                                           int* __restrict__ block_off,
                                                           int* __restrict__ row_start) {
    __shared__ int lds[256];
    int t = threadIdx.x;
    int v = (t < NSB) ? block_sums[t] : 0;
    lds[t] = v;
    __syncthreads();
    for (int off = 1; off < 256; off <<= 1) {
        int x = (t >= off) ? lds[t - off] : 0;
        __syncthreads();
        lds[t] += x;
        __syncthreads();
    }
    if (t < NSB) block_off[t] = lds[t] - v;  // exclusive
    if (t == 255) row_start[NN] = lds[255];  // total = NE
}

__global__ __launch_bounds__(SBLK) void scan_final_kernel(const int* __restrict__ counts,
                                                          const int* __restrict__ block_off,
                                                          int* __restrict__ row_start,
                                                          int* __restrict__ cursor) {
    __shared__ int lds[SBLK];
    int i = blockIdx.x * SBLK + threadIdx.x;
    int v = (i < NN) ? counts[i] : 0;
    lds[threadIdx.x] = v;
    __syncthreads();
    for (int off = 1; off < SBLK; off <<= 1) {
        int x = (threadIdx.x >= off) ? lds[threadIdx.x - off] : 0;
        __syncthreads();
        lds[threadIdx.x] += x;
        __syncthreads();
    }
    if (i < NN) {
        int excl = block_off[blockIdx.x] + lds[threadIdx.x] - v;
        row_start[i] = excl;
        cursor[i] = excl;
    }
}

__global__ void fill_kernel(const int* __restrict__ ei, const int* __restrict__ flag,
                            int* __restrict__ cursor, int* __restrict__ csr_src) {
    int e = blockIdx.x * blockDim.x + threadIdx.x;
    if (e >= NE) return;
    int src, dst;
    load_edge(ei, flag, e, src, dst);
    int slot = atomicAdd(cursor + dst, 1);
    csr_src[slot] = src;
}

// ---------------------------------------------------------------------------
__global__ void init_h_kernel(const float* __restrict__ z, f16* __restrict__ h) {
    int i = blockIdx.x * blockDim.x + threadIdx.x;
    if (i * 2 >= NN * D) return;
    f32x2 v = *(const f32x2*)(z + i * 2);
    f16x2 o = {(f16)v[0], (f16)v[1]};
    *(f16x2*)(h + i * 2) = o;
}

__global__ void finalize_kernel(const f16* __restrict__ h, float* __restrict__ out) {
    int i = blockIdx.x * blockDim.x + threadIdx.x;
    if (i * 2 >= NN * D) return;
    f16x2 v = *(const f16x2*)(h + i * 2);
    f32x2 o = {(float)v[0], (float)v[1]};
    *(f32x2*)(out + i * 2) = o;
}

// ---------------------------------------------------------------------------
// Gather: one wave per dst row, 4 edge slots x 16 lanes (f16x8 each).
__global__ __launch_bounds__(256) void gather_kernel(
    const f16* __restrict__ h, const int* __restrict__ row_start,
    const int* __restrict__ csr_src, f16* __restrict__ agg) {
    int row = blockIdx.x * 4 + (threadIdx.x >> 6);
    if (row >= NN) return;
    int lane = threadIdx.x & 63;
    int eslot = lane >> 4;       // 0..3
    int c0 = (lane & 15) * 8;    // col base (8 f16 = 16 B)
    int beg = row_start[row], end = row_start[row + 1];
    float acc[8] = {0.f, 0.f, 0.f, 0.f, 0.f, 0.f, 0.f, 0.f};
    for (int base = beg; base + eslot < end; base += 4) {
        int s = csr_src[base + eslot];
        f16x8 v = *(const f16x8*)(h + s * D + c0);
#pragma unroll
        for (int j = 0; j < 8; ++j) acc[j] += (float)v[j];
    }
#pragma unroll
    for (int j = 0; j < 8; ++j) {
        acc[j] += __shfl_xor(acc[j], 16, 64);
        acc[j] += __shfl_xor(acc[j], 32, 64);
    }
    if (lane < 16) {
        f16x8 o;
#pragma unroll
        for (int j = 0; j < 8; ++j) o[j] = (f16)acc[j];
        *(f16x8*)(agg + row * D + c0) = o;
    }
}

// ---------------------------------------------------------------------------
// WcT[l][g][c] = sum_j weight[l][c][j] * w_ih[g][j] (fp16); whh fp16.
__global__ void precompute_weights(const float* __restrict__ weight,
                                   const float* __restrict__ w_ih,
                                   const float* __restrict__ w_hh,
                                   f16* __restrict__ wct, f16* __restrict__ whh) {
    int l = blockIdx.x / G3;
    int g = blockIdx.x % G3;
    int c = threadIdx.x;  // 0..127
    __shared__ float wih_row[D];
    wih_row[c] = w_ih[g * D + c];
    __syncthreads();
    const float* wrow = weight + ((long long)l * D + c) * D;
    float acc = 0.f;
#pragma unroll 8
    for (int j = 0; j < D; ++j) acc += wrow[j] * wih_row[j];
    wct[((long long)l * G3 + g) * D + c] = (f16)acc;
    if (l == 0) whh[g * D + c] = (f16)w_hh[g * D + c];
}

// ---------------------------------------------------------------------------
// Fused GRU with LDS-staged weights. Block = 4 waves x 16 rows = 64 rows.
// Per d-tile: block stages 6 weight panels (24KB, XOR-swizzled) into LDS
// once; all 4 waves read via ds_read_b128.
// Swizzle involution (16B units within a row): unit' = unit ^ (row&7).
// Writer: byte (row*256 + unit*16) ^ ((row&7)<<4)  [bits 4-7 = unit]
// Reader: byte  row*256 + ((unit ^ (row&7)) << 4)  [XOR on FULL unit index;
//         the round-8 bug added the XOR'd base, carrying into row bits]
#define TM 64
#define MFMA_F16 __builtin_amdgcn_mfma_f32_16x16x32_f16
__global__ __launch_bounds__(256) void gru_fused_kernel(
    const f16* __restrict__ agg, const f16* __restrict__ hin, f16* __restrict__ hout,
    const f16* __restrict__ wct, const f16* __restrict__ whh,
    const float* __restrict__ b_ih, const float* __restrict__ b_hh, int ndt) {
    __shared__ char wlds[6 * 4096];  // [panel][16 rows][128 f16], swizzled
    const int tid = threadIdx.x;
    const int lane = tid & 63;
    const int wv = tid >> 6;
    const int fr = lane & 15;  // A row / B col / D col
    const int kg = lane >> 4;  // k-group
    const int m0 = blockIdx.x * TM;
    const int dt0 = blockIdx.y * ndt;

    int arow = m0 + wv * 16 + fr;
    int arc = arow < NN ? arow : NN - 1;
    const int abase = arc * D;

    f16x8 fa[4], fh[4];
#pragma unroll
    for (int ks = 0; ks < 4; ++ks) {
        int k0 = ks * 32 + kg * 8;
        fa[ks] = *(const f16x8*)(agg + abase + k0);
        fh[ks] = *(const f16x8*)(hin + abase + k0);
    }

    // staging constants (thread tid covers 16B unit tid of each panel)
    const int sr = tid >> 4;                      // weight row 0..15
    const int sc = (tid & 15) * 8;                // col base (f16)
    const int wb = (tid * 16) ^ ((sr & 7) << 4);  // swizzled byte in panel

#pragma unroll 1
    for (int dti = 0; dti < ndt; ++dti) {
        const int dt = dt0 + dti;
        const int gr = dt * 16;  // weight-row base of this d-tile
        if (dti) __syncthreads();  // waves done reading previous panels
        {
            f16x8 v0 = *(const f16x8*)(wct + (gr + sr) * D + sc);
            f16x8 v1 = *(const f16x8*)(wct + (128 + gr + sr) * D + sc);
            f16x8 v2 = *(const f16x8*)(wct + (256 + gr + sr) * D + sc);
            f16x8 v3 = *(const f16x8*)(whh + (gr + sr) * D + sc);
            f16x8 v4 = *(const f16x8*)(whh + (128 + gr + sr) * D + sc);
            f16x8 v5 = *(const f16x8*)(whh + (256 + gr + sr) * D + sc);
            *(f16x8*)(wlds + 0 * 4096 + wb) = v0;
            *(f16x8*)(wlds + 1 * 4096 + wb) = v1;
            *(f16x8*)(wlds + 2 * 4096 + wb) = v2;
            *(f16x8*)(wlds + 3 * 4096 + wb) = v3;
            *(f16x8*)(wlds + 4 * 4096 + wb) = v4;
            *(f16x8*)(wlds + 5 * 4096 + wb) = v5;
        }
        __syncthreads();

        f32x4 a_ir = {0, 0, 0, 0}, a_iz = {0, 0, 0, 0}, a_in = {0, 0, 0, 0};
        f32x4 a_hr = {0, 0, 0, 0}, a_hz = {0, 0, 0, 0}, a_hn = {0, 0, 0, 0};
#pragma unroll
        for (int ks = 0; ks < 4; ++ks) {
            // unit index of this k-slice; XOR the FULL unit with row&7
            const int kb = fr * 256 + (((ks * 4 + kg) ^ (fr & 7)) << 4);
            f16x8 bir = *(const f16x8*)(wlds + 0 * 4096 + kb);
            f16x8 biz = *(const f16x8*)(wlds + 1 * 4096 + kb);
            f16x8 bin = *(const f16x8*)(wlds + 2 * 4096 + kb);
            f16x8 bhr = *(const f16x8*)(wlds + 3 * 4096 + kb);
            f16x8 bhz = *(const f16x8*)(wlds + 4 * 4096 + kb);
            f16x8 bhn = *(const f16x8*)(wlds + 5 * 4096 + kb);
            a_ir = MFMA_F16(fa[ks], bir, a_ir, 0, 0, 0);
            a_iz = MFMA_F16(fa[ks], biz, a_iz, 0, 0, 0);
            a_in = MFMA_F16(fa[ks], bin, a_in, 0, 0, 0);
            a_hr = MFMA_F16(fh[ks], bhr, a_hr, 0, 0, 0);
            a_hz = MFMA_F16(fh[ks], bhz, a_hz, 0, 0, 0);
            a_hn = MFMA_F16(fh[ks], bhn, a_hn, 0, 0, 0);
        }
        // Epilogue: C/D layout col = lane&15, row = (lane>>4)*4 + j
        const int d = gr + fr;
        float bir_ = b_ih[d], biz_ = b_ih[128 + d], bin_ = b_ih[256 + d];
        float bhr_ = b_hh[d], bhz_ = b_hh[128 + d], bhn_ = b_hh[256 + d];
#pragma unroll
        for (int j = 0; j < 4; ++j) {
            int row = m0 + wv * 16 + kg * 4 + j;
            if (row >= NN) continue;
            float ir = a_ir[j] + bir_, iz = a_iz[j] + biz_, in_ = a_in[j] + bin_;
            float hr = a_hr[j] + bhr_, hz = a_hz[j] + bhz_, hn = a_hn[j] + bhn_;
            float r = 1.f / (1.f + __expf(-(ir + hr)));
            float zz = 1.f / (1.f + __expf(-(iz + hz)));
            float e2 = __expf(2.f * (in_ + r * hn));
            float nn = 1.f - 2.f / (e2 + 1.f);  // tanh
            int off = row * D + d;
            float hold = (float)hin[off];
            float hnew = (1.f - zz) * nn + zz * hold;
            hout[off] = (f16)hnew;
        }
    }
}

// ---------------------------------------------------------------------------
extern "C" void kernel_launch(void* const* d_in, const int* in_sizes, int n_in,
                              void* d_out, int out_size, void* d_ws, size_t ws_size,
                              hipStream_t stream) {
    const float* z = (const float*)d_in[0];
    const int* ei = (const int*)d_in[1];
    const float* weight = (const float*)d_in[2];
    const float* w_ih = (const float*)d_in[3];
    const float* w_hh = (const float*)d_in[4];
    const float* b_ih = (const float*)d_in[5];
    const float* b_hh = (const float*)d_in[6];
    float* out = (float*)d_out;

    char* ws = (char*)d_ws;
    size_t off = 0;
    f16* wct = (f16*)(ws + off); off += 294912;
    f16* whh = (f16*)(ws + off); off += 98304;
    int* flag       = (int*)(ws + off); off += 256;
    int* counts     = (int*)(ws + off); off += (size_t)NN * 4;
    int* cursor     = (int*)(ws + off); off += (size_t)NN * 4;
    int* row_start  = (int*)(ws + off); off += (size_t)(NN + 16) * 4;
    int* block_sums = (int*)(ws + off); off += (size_t)NSB * 4;
    int* block_off  = (int*)(ws + off); off += (size_t)NSB * 4;
    int* csr_src    = (int*)(ws + off); off += (size_t)NE * 4;
    f16* agg  = (f16*)(ws + off); off += (size_t)NN * D * 2;
    f16* hA   = (f16*)(ws + off); off += (size_t)NN * D * 2;
    size_t off_min = off;
    f16* hB   = (f16*)(ws + off); off += (size_t)NN * D * 2;
    const bool split = (ws_size >= off);  // room for ping-pong buffer?
    if (!split) { hB = hA; (void)off_min; }

    detect_i64_kernel<<<1, 256, 0, stream>>>(ei, flag);
    hipMemsetAsync(counts, 0, (size_t)NN * 4, stream);
    hist_kernel<<<(NE + 255) / 256, 256, 0, stream>>>(ei, flag, counts);
    scan_reduce_kernel<<<NSB, SBLK, 0, stream>>>(counts, block_sums);
    scan_offsets_kernel<<<1, 256, 0, stream>>>(block_sums, block_off, row_start);
    scan_final_kernel<<<NSB, SBLK, 0, stream>>>(counts, block_off, row_start, cursor);
    fill_kernel<<<(NE + 255) / 256, 256, 0, stream>>>(ei, flag, cursor, csr_src);
    precompute_weights<<<NL * G3, 128, 0, stream>>>(weight, w_ih, w_hh, wct, whh);
    const int npair = NN * D / 2;
    init_h_kernel<<<(npair + 255) / 256, 256, 0, stream>>>(z, hA);

    const int ndt = split ? 1 : 8;
    const dim3 gg((NN + TM - 1) / TM, split ? 8 : 1);
    const f16* cin = hA;
    for (int l = 0; l < NL; ++l) {
        gather_kernel<<<(NN + 3) / 4, 256, 0, stream>>>(cin, row_start, csr_src, agg);
        f16* cout = split ? ((cin == hA) ? hB : hA) : (f16*)cin;
        long long woff = (long long)l * G3 * D;
        gru_fused_kernel<<<gg, 256, 0, stream>>>(agg, cin, cout, wct + woff, whh,
                                                 b_ih, b_hh, ndt);
        cin = cout;
    }
    finalize_kernel<<<(npair + 255) / 256, 256, 0, stream>>>(cin, out);
}

// Round 10
// 309.431 us; speedup vs baseline: 15.0753x; 1.2124x over previous
//
#include <hip/hip_runtime.h>
#include <hip/hip_bf16.h>

#define NN 50000
#define NE 800000
#define D 128
#define NL 3
#define G3 384

typedef __attribute__((ext_vector_type(4))) float f32x4;
typedef __attribute__((ext_vector_type(2))) float f32x2;
typedef _Float16 f16;
typedef __attribute__((ext_vector_type(8))) _Float16 f16x8;
typedef __attribute__((ext_vector_type(2))) _Float16 f16x2;

// ---------------------------------------------------------------------------
__global__ void detect_i64_kernel(const int* __restrict__ ei, int* __restrict__ flag) {
    __shared__ int any_nz;
    if (threadIdx.x == 0) any_nz = 0;
    __syncthreads();
    int v = ei[threadIdx.x * 2 + 1];
    if (v != 0) atomicOr(&any_nz, 1);
    __syncthreads();
    if (threadIdx.x == 0) *flag = (any_nz == 0) ? 1 : 0;  // 1 => int64
}

static __device__ __forceinline__ void load_edge(const int* ei, const int* flag, int e,
                                                 int& src, int& dst) {
    if (*flag) {
        src = ei[2LL * e];
        dst = ei[2LL * (NE + e)];
    } else {
        src = ei[e];
        dst = ei[NE + e];
    }
}

// ---------------------------------------------------------------------------
// CSR build: histogram(+rank) -> parallel 3-phase scan -> atomic-free fill.
__global__ void hist_kernel(const int* __restrict__ ei, const int* __restrict__ flag,
                            int* __restrict__ counts, unsigned short* __restrict__ rank16) {
    int e = blockIdx.x * blockDim.x + threadIdx.x;
    if (e >= NE) return;
    int src, dst;
    load_edge(ei, flag, e, src, dst);
    rank16[e] = (unsigned short)atomicAdd(counts + dst, 1);
}

#define SBLK 256
#define NSB ((NN + SBLK - 1) / SBLK)  // 196

__global__ __launch_bounds__(SBLK) void scan_reduce_kernel(const int* __restrict__ counts,
                                                           int* __restrict__ block_sums) {
    __shared__ int lds[SBLK];
    int i = blockIdx.x * SBLK + threadIdx.x;
    lds[threadIdx.x] = (i < NN) ? counts[i] : 0;
    __syncthreads();
    for (int off = SBLK / 2; off > 0; off >>= 1) {
        if (threadIdx.x < off) lds[threadIdx.x] += lds[threadIdx.x + off];
        __syncthreads();
    }
    if (threadIdx.x == 0) block_sums[blockIdx.x] = lds[0];
}

__global__ __launch_bounds__(256) void scan_offsets_kernel(const int* __restrict__ block_sums,
                                                           int* __restrict__ block_off,
                                                           int* __restrict__ row_start) {
    __shared__ int lds[256];
    int t = threadIdx.x;
    int v = (t < NSB) ? block_sums[t] : 0;
    lds[t] = v;
    __syncthreads();
    for (int off = 1; off < 256; off <<= 1) {
        int x = (t >= off) ? lds[t - off] : 0;
        __syncthreads();
        lds[t] += x;
        __syncthreads();
    }
    if (t < NSB) block_off[t] = lds[t] - v;  // exclusive
    if (t == 255) row_start[NN] = lds[255];  // total = NE
}

__global__ __launch_bounds__(SBLK) void scan_final_kernel(const int* __restrict__ counts,
                                                          const int* __restrict__ block_off,
                                                          int* __restrict__ row_start) {
    __shared__ int lds[SBLK];
    int i = blockIdx.x * SBLK + threadIdx.x;
    int v = (i < NN) ? counts[i] : 0;
    lds[threadIdx.x] = v;
    __syncthreads();
    for (int off = 1; off < SBLK; off <<= 1) {
        int x = (threadIdx.x >= off) ? lds[threadIdx.x - off] : 0;
        __syncthreads();
        lds[threadIdx.x] += x;
        __syncthreads();
    }
    if (i < NN) row_start[i] = block_off[blockIdx.x] + lds[threadIdx.x] - v;
}

// Atomic-free fill: slot = row_start[dst] + rank16[e].
__global__ void fill_kernel(const int* __restrict__ ei, const int* __restrict__ flag,
                            const int* __restrict__ row_start,
                            const unsigned short* __restrict__ rank16,
                            unsigned short* __restrict__ csr16) {
    int e = blockIdx.x * blockDim.x + threadIdx.x;
    if (e >= NE) return;
    int src, dst;
    load_edge(ei, flag, e, src, dst);
    csr16[row_start[dst] + (int)rank16[e]] = (unsigned short)src;
}

// ---------------------------------------------------------------------------
__global__ void init_h_kernel(const float* __restrict__ z, f16* __restrict__ h) {
    int i = blockIdx.x * blockDim.x + threadIdx.x;
    if (i * 2 >= NN * D) return;
    f32x2 v = *(const f32x2*)(z + i * 2);
    f16x2 o = {(f16)v[0], (f16)v[1]};
    *(f16x2*)(h + i * 2) = o;
}

// ---------------------------------------------------------------------------
// Gather: one wave per dst row, 4 edge slots x 16 lanes (f16x8 each).
__global__ __launch_bounds__(256) void gather_kernel(
    const f16* __restrict__ h, const int* __restrict__ row_start,
    const unsigned short* __restrict__ csr16, f16* __restrict__ agg) {
    int row = blockIdx.x * 4 + (threadIdx.x >> 6);
    if (row >= NN) return;
    int lane = threadIdx.x & 63;
    int eslot = lane >> 4;       // 0..3
    int c0 = (lane & 15) * 8;    // col base (8 f16 = 16 B)
    int beg = row_start[row], end = row_start[row + 1];
    float acc[8] = {0.f, 0.f, 0.f, 0.f, 0.f, 0.f, 0.f, 0.f};
    for (int base = beg; base + eslot < end; base += 4) {
        int s = (int)csr16[base + eslot];
        f16x8 v = *(const f16x8*)(h + s * D + c0);
#pragma unroll
        for (int j = 0; j < 8; ++j) acc[j] += (float)v[j];
    }
#pragma unroll
    for (int j = 0; j < 8; ++j) {
        acc[j] += __shfl_xor(acc[j], 16, 64);
        acc[j] += __shfl_xor(acc[j], 32, 64);
    }
    if (lane < 16) {
        f16x8 o;
#pragma unroll
        for (int j = 0; j < 8; ++j) o[j] = (f16)acc[j];
        *(f16x8*)(agg + row * D + c0) = o;
    }
}

// ---------------------------------------------------------------------------
// WcT[l][g][c] = sum_j weight[l][c][j] * w_ih[g][j] (fp16); whh fp16.
__global__ void precompute_weights(const float* __restrict__ weight,
                                   const float* __restrict__ w_ih,
                                   const float* __restrict__ w_hh,
                                   f16* __restrict__ wct, f16* __restrict__ whh) {
    int l = blockIdx.x / G3;
    int g = blockIdx.x % G3;
    int c = threadIdx.x;  // 0..127
    __shared__ float wih_row[D];
    wih_row[c] = w_ih[g * D + c];
    __syncthreads();
    const float* wrow = weight + ((long long)l * D + c) * D;
    float acc = 0.f;
#pragma unroll 8
    for (int j = 0; j < D; ++j) acc += wrow[j] * wih_row[j];
    wct[((long long)l * G3 + g) * D + c] = (f16)acc;
    if (l == 0) whh[g * D + c] = (f16)w_hh[g * D + c];
}

// ---------------------------------------------------------------------------
// Fused GRU with LDS-staged weights. Block = 8 waves x 16 rows = 128 rows.
// Per d-tile: block stages 6 weight panels (24KB, XOR-swizzled, 3 units/thread)
// into LDS once; all 8 waves read via ds_read_b128.
// Swizzle involution (16B units within a 16x256B panel): unit' = unit^(row&7).
// If out_f32 != nullptr (last layer): write f32 to out_f32 instead of f16 hout.
#define TMG 128
#define MFMA_F16 __builtin_amdgcn_mfma_f32_16x16x32_f16
__global__ __launch_bounds__(512) void gru_fused_kernel(
    const f16* __restrict__ agg, const f16* __restrict__ hin, f16* __restrict__ hout,
    const f16* __restrict__ wct, const f16* __restrict__ whh,
    const float* __restrict__ b_ih, const float* __restrict__ b_hh, int ndt,
    float* __restrict__ out_f32) {
    __shared__ char wlds[6 * 4096];  // [panel][16 rows][128 f16], swizzled
    const int tid = threadIdx.x;
    const int lane = tid & 63;
    const int wv = tid >> 6;   // 0..7
    const int fr = lane & 15;  // A row / B col / D col
    const int kg = lane >> 4;  // k-group
    const int m0 = blockIdx.x * TMG;
    const int dt0 = blockIdx.y * ndt;

    int arow = m0 + wv * 16 + fr;
    int arc = arow < NN ? arow : NN - 1;
    const int abase = arc * D;

    f16x8 fa[4], fh[4];
#pragma unroll
    for (int ks = 0; ks < 4; ++ks) {
        int k0 = ks * 32 + kg * 8;
        fa[ks] = *(const f16x8*)(agg + abase + k0);
        fh[ks] = *(const f16x8*)(hin + abase + k0);
    }

#pragma unroll 1
    for (int dti = 0; dti < ndt; ++dti) {
        const int dt = dt0 + dti;
        const int gr = dt * 16;  // weight-row base of this d-tile
        if (dti) __syncthreads();  // waves done reading previous panels
        // Stage 6 panels (1536 16B units) with 512 threads: 3 units each.
#pragma unroll
        for (int p3 = 0; p3 < 3; ++p3) {
            int unit = tid + p3 * 512;  // 0..1535
            int panel = unit >> 8;      // 0..5
            int u = unit & 255;
            int sr = u >> 4;            // row 0..15
            int sc = (u & 15) * 8;      // col base (f16)
            const f16* srcp = (panel < 3)
                                  ? wct + (panel * 128 + gr + sr) * D + sc
                                  : whh + ((panel - 3) * 128 + gr + sr) * D + sc;
            int wb = (u * 16) ^ ((sr & 7) << 4);
            *(f16x8*)(wlds + panel * 4096 + wb) = *(const f16x8*)srcp;
        }
        __syncthreads();

        f32x4 a_ir = {0, 0, 0, 0}, a_iz = {0, 0, 0, 0}, a_in = {0, 0, 0, 0};
        f32x4 a_hr = {0, 0, 0, 0}, a_hz = {0, 0, 0, 0}, a_hn = {0, 0, 0, 0};
#pragma unroll
        for (int ks = 0; ks < 4; ++ks) {
            // unit index of this k-slice; XOR the FULL unit with row&7
            const int kb = fr * 256 + (((ks * 4 + kg) ^ (fr & 7)) << 4);
            f16x8 bir = *(const f16x8*)(wlds + 0 * 4096 + kb);
            f16x8 biz = *(const f16x8*)(wlds + 1 * 4096 + kb);
            f16x8 bin = *(const f16x8*)(wlds + 2 * 4096 + kb);
            f16x8 bhr = *(const f16x8*)(wlds + 3 * 4096 + kb);
            f16x8 bhz = *(const f16x8*)(wlds + 4 * 4096 + kb);
            f16x8 bhn = *(const f16x8*)(wlds + 5 * 4096 + kb);
            a_ir = MFMA_F16(fa[ks], bir, a_ir, 0, 0, 0);
            a_iz = MFMA_F16(fa[ks], biz, a_iz, 0, 0, 0);
            a_in = MFMA_F16(fa[ks], bin, a_in, 0, 0, 0);
            a_hr = MFMA_F16(fh[ks], bhr, a_hr, 0, 0, 0);
            a_hz = MFMA_F16(fh[ks], bhz, a_hz, 0, 0, 0);
            a_hn = MFMA_F16(fh[ks], bhn, a_hn, 0, 0, 0);
        }
        // Epilogue: C/D layout col = lane&15, row = (lane>>4)*4 + j
        const int d = gr + fr;
        float bir_ = b_ih[d], biz_ = b_ih[128 + d], bin_ = b_ih[256 + d];
        float bhr_ = b_hh[d], bhz_ = b_hh[128 + d], bhn_ = b_hh[256 + d];
#pragma unroll
        for (int j = 0; j < 4; ++j) {
            int row = m0 + wv * 16 + kg * 4 + j;
            if (row >= NN) continue;
            float ir = a_ir[j] + bir_, iz = a_iz[j] + biz_, in_ = a_in[j] + bin_;
            float hr = a_hr[j] + bhr_, hz = a_hz[j] + bhz_, hn = a_hn[j] + bhn_;
            float r = 1.f / (1.f + __expf(-(ir + hr)));
            float zz = 1.f / (1.f + __expf(-(iz + hz)));
            float e2 = __expf(2.f * (in_ + r * hn));
            float nn = 1.f - 2.f / (e2 + 1.f);  // tanh
            int off = row * D + d;
            float hold = (float)hin[off];
            float hnew = (1.f - zz) * nn + zz * hold;
            if (out_f32)
                out_f32[off] = hnew;
            else
                hout[off] = (f16)hnew;
        }
    }
}

// ---------------------------------------------------------------------------
extern "C" void kernel_launch(void* const* d_in, const int* in_sizes, int n_in,
                              void* d_out, int out_size, void* d_ws, size_t ws_size,
                              hipStream_t stream) {
    const float* z = (const float*)d_in[0];
    const int* ei = (const int*)d_in[1];
    const float* weight = (const float*)d_in[2];
    const float* w_ih = (const float*)d_in[3];
    const float* w_hh = (const float*)d_in[4];
    const float* b_ih = (const float*)d_in[5];
    const float* b_hh = (const float*)d_in[6];
    float* out = (float*)d_out;

    char* ws = (char*)d_ws;
    size_t off = 0;
    f16* wct = (f16*)(ws + off); off += 294912;
    f16* whh = (f16*)(ws + off); off += 98304;
    int* flag       = (int*)(ws + off); off += 256;
    int* counts     = (int*)(ws + off); off += (size_t)NN * 4;
    int* row_start  = (int*)(ws + off); off += (size_t)(NN + 16) * 4;
    int* block_sums = (int*)(ws + off); off += (size_t)NSB * 4;
    int* block_off  = (int*)(ws + off); off += (size_t)NSB * 4;
    unsigned short* rank16 = (unsigned short*)(ws + off); off += (size_t)NE * 2;
    unsigned short* csr16  = (unsigned short*)(ws + off); off += (size_t)NE * 2;
    f16* agg  = (f16*)(ws + off); off += (size_t)NN * D * 2;
    f16* hA   = (f16*)(ws + off); off += (size_t)NN * D * 2;
    size_t off_min = off;
    f16* hB   = (f16*)(ws + off); off += (size_t)NN * D * 2;
    const bool split = (ws_size >= off);  // room for ping-pong buffer?
    if (!split) { hB = hA; (void)off_min; }

    detect_i64_kernel<<<1, 256, 0, stream>>>(ei, flag);
    hipMemsetAsync(counts, 0, (size_t)NN * 4, stream);
    hist_kernel<<<(NE + 255) / 256, 256, 0, stream>>>(ei, flag, counts, rank16);
    scan_reduce_kernel<<<NSB, SBLK, 0, stream>>>(counts, block_sums);
    scan_offsets_kernel<<<1, 256, 0, stream>>>(block_sums, block_off, row_start);
    scan_final_kernel<<<NSB, SBLK, 0, stream>>>(counts, block_off, row_start);
    fill_kernel<<<(NE + 255) / 256, 256, 0, stream>>>(ei, flag, row_start, rank16, csr16);
    precompute_weights<<<NL * G3, 128, 0, stream>>>(weight, w_ih, w_hh, wct, whh);
    const int npair = NN * D / 2;
    init_h_kernel<<<(npair + 255) / 256, 256, 0, stream>>>(z, hA);

    const int ndt = split ? 2 : 8;
    const dim3 gg((NN + TMG - 1) / TMG, split ? 4 : 1);
    const f16* cin = hA;
    for (int l = 0; l < NL; ++l) {
        gather_kernel<<<(NN + 3) / 4, 256, 0, stream>>>(cin, row_start, csr16, agg);
        f16* cout = split ? ((cin == hA) ? hB : hA) : (f16*)cin;
        long long woff = (long long)l * G3 * D;
        float* last_out = (l == NL - 1) ? out : nullptr;
        gru_fused_kernel<<<gg, 512, 0, stream>>>(agg, cin, cout, wct + woff, whh,
                                                 b_ih, b_hh, ndt, last_out);
        cin = cout;
    }
}

// Round 11
// 297.616 us; speedup vs baseline: 15.6737x; 1.0397x over previous
//
#include <hip/hip_runtime.h>
#include <hip/hip_bf16.h>

#define NN 50000
#define NE 800000
#define D 128
#define NL 3
#define G3 384

typedef __attribute__((ext_vector_type(4))) float f32x4;
typedef __attribute__((ext_vector_type(2))) float f32x2;
typedef _Float16 f16;
typedef __attribute__((ext_vector_type(8))) _Float16 f16x8;
typedef __attribute__((ext_vector_type(2))) _Float16 f16x2;

// ---------------------------------------------------------------------------
__global__ void detect_i64_kernel(const int* __restrict__ ei, int* __restrict__ flag) {
    __shared__ int any_nz;
    if (threadIdx.x == 0) any_nz = 0;
    __syncthreads();
    int v = ei[threadIdx.x * 2 + 1];
    if (v != 0) atomicOr(&any_nz, 1);
    __syncthreads();
    if (threadIdx.x == 0) *flag = (any_nz == 0) ? 1 : 0;  // 1 => int64
}

static __device__ __forceinline__ void load_edge(const int* ei, const int* flag, int e,
                                                 int& src, int& dst) {
    if (*flag) {
        src = ei[2LL * e];
        dst = ei[2LL * (NE + e)];
    } else {
        src = ei[e];
        dst = ei[NE + e];
    }
}

// ---------------------------------------------------------------------------
// CSR build: histogram(+rank) -> parallel 3-phase scan -> atomic-free fill.
__global__ void hist_kernel(const int* __restrict__ ei, const int* __restrict__ flag,
                            int* __restrict__ counts, unsigned short* __restrict__ rank16) {
    int e = blockIdx.x * blockDim.x + threadIdx.x;
    if (e >= NE) return;
    int src, dst;
    load_edge(ei, flag, e, src, dst);
    rank16[e] = (unsigned short)atomicAdd(counts + dst, 1);
}

#define SBLK 256
#define NSB ((NN + SBLK - 1) / SBLK)  // 196

__global__ __launch_bounds__(SBLK) void scan_reduce_kernel(const int* __restrict__ counts,
                                                           int* __restrict__ block_sums) {
    __shared__ int lds[SBLK];
    int i = blockIdx.x * SBLK + threadIdx.x;
    lds[threadIdx.x] = (i < NN) ? counts[i] : 0;
    __syncthreads();
    for (int off = SBLK / 2; off > 0; off >>= 1) {
        if (threadIdx.x < off) lds[threadIdx.x] += lds[threadIdx.x + off];
        __syncthreads();
    }
    if (threadIdx.x == 0) block_sums[blockIdx.x] = lds[0];
}

__global__ __launch_bounds__(256) void scan_offsets_kernel(const int* __restrict__ block_sums,
                                                           int* __restrict__ block_off,
                                                           int* __restrict__ row_start) {
    __shared__ int lds[256];
    int t = threadIdx.x;
    int v = (t < NSB) ? block_sums[t] : 0;
    lds[t] = v;
    __syncthreads();
    for (int off = 1; off < 256; off <<= 1) {
        int x = (t >= off) ? lds[t - off] : 0;
        __syncthreads();
        lds[t] += x;
        __syncthreads();
    }
    if (t < NSB) block_off[t] = lds[t] - v;  // exclusive
    if (t == 255) row_start[NN] = lds[255];  // total = NE
}

__global__ __launch_bounds__(SBLK) void scan_final_kernel(const int* __restrict__ counts,
                                                          const int* __restrict__ block_off,
                                                          int* __restrict__ row_start) {
    __shared__ int lds[SBLK];
    int i = blockIdx.x * SBLK + threadIdx.x;
    int v = (i < NN) ? counts[i] : 0;
    lds[threadIdx.x] = v;
    __syncthreads();
    for (int off = 1; off < SBLK; off <<= 1) {
        int x = (threadIdx.x >= off) ? lds[threadIdx.x - off] : 0;
        __syncthreads();
        lds[threadIdx.x] += x;
        __syncthreads();
    }
    if (i < NN) row_start[i] = block_off[blockIdx.x] + lds[threadIdx.x] - v;
}

// Atomic-free fill: slot = row_start[dst] + rank16[e].
__global__ void fill_kernel(const int* __restrict__ ei, const int* __restrict__ flag,
                            const int* __restrict__ row_start,
                            const unsigned short* __restrict__ rank16,
                            unsigned short* __restrict__ csr16) {
    int e = blockIdx.x * blockDim.x + threadIdx.x;
    if (e >= NE) return;
    int src, dst;
    load_edge(ei, flag, e, src, dst);
    csr16[row_start[dst] + (int)rank16[e]] = (unsigned short)src;
}

// ---------------------------------------------------------------------------
__global__ void init_h_kernel(const float* __restrict__ z, f16* __restrict__ h) {
    int i = blockIdx.x * blockDim.x + threadIdx.x;
    if (i * 2 >= NN * D) return;
    f32x2 v = *(const f32x2*)(z + i * 2);
    f16x2 o = {(f16)v[0], (f16)v[1]};
    *(f16x2*)(h + i * 2) = o;
}

// ---------------------------------------------------------------------------
// Gather: one wave per dst row; lanes split 4 eslots x 16 (f16x8 chunks).
// Each lane handles 2 edge slots (eslot, eslot+4) per iter (step 8) with
// dual accumulators for 2-deep MLP; tail via 4-slot steps.
__global__ __launch_bounds__(256) void gather_kernel(
    const f16* __restrict__ h, const int* __restrict__ row_start,
    const unsigned short* __restrict__ csr16, f16* __restrict__ agg) {
    int row = blockIdx.x * 4 + (threadIdx.x >> 6);
    if (row >= NN) return;
    int lane = threadIdx.x & 63;
    int eslot = lane >> 4;       // 0..3
    int c0 = (lane & 15) * 8;    // col base (8 f16 = 16 B)
    int beg = row_start[row], end = row_start[row + 1];
    float acc[8] = {0.f, 0.f, 0.f, 0.f, 0.f, 0.f, 0.f, 0.f};
    float acc2[8] = {0.f, 0.f, 0.f, 0.f, 0.f, 0.f, 0.f, 0.f};
    int e = beg;
    for (; e + 7 < end; e += 8) {
        int s0 = (int)csr16[e + eslot];
        int s1 = (int)csr16[e + eslot + 4];
        f16x8 v0 = *(const f16x8*)(h + s0 * D + c0);
        f16x8 v1 = *(const f16x8*)(h + s1 * D + c0);
#pragma unroll
        for (int j = 0; j < 8; ++j) { acc[j] += (float)v0[j]; acc2[j] += (float)v1[j]; }
    }
    for (; e + eslot < end; e += 4) {
        int s = (int)csr16[e + eslot];
        f16x8 v = *(const f16x8*)(h + s * D + c0);
#pragma unroll
        for (int j = 0; j < 8; ++j) acc[j] += (float)v[j];
    }
#pragma unroll
    for (int j = 0; j < 8; ++j) {
        acc[j] += acc2[j];
        acc[j] += __shfl_xor(acc[j], 16, 64);
        acc[j] += __shfl_xor(acc[j], 32, 64);
    }
    if (lane < 16) {
        f16x8 o;
#pragma unroll
        for (int j = 0; j < 8; ++j) o[j] = (f16)acc[j];
        *(f16x8*)(agg + row * D + c0) = o;
    }
}

// ---------------------------------------------------------------------------
// WcT[l][g][c] = sum_j weight[l][c][j] * w_ih[g][j] (fp16); whh fp16.
__global__ void precompute_weights(const float* __restrict__ weight,
                                   const float* __restrict__ w_ih,
                                   const float* __restrict__ w_hh,
                                   f16* __restrict__ wct, f16* __restrict__ whh) {
    int l = blockIdx.x / G3;
    int g = blockIdx.x % G3;
    int c = threadIdx.x;  // 0..127
    __shared__ float wih_row[D];
    wih_row[c] = w_ih[g * D + c];
    __syncthreads();
    const float* wrow = weight + ((long long)l * D + c) * D;
    float acc = 0.f;
#pragma unroll 8
    for (int j = 0; j < D; ++j) acc += wrow[j] * wih_row[j];
    wct[((long long)l * G3 + g) * D + c] = (f16)acc;
    if (l == 0) whh[g * D + c] = (f16)w_hh[g * D + c];
}

// ---------------------------------------------------------------------------
// Fused GRU with LDS-staged weights. Block = 8 waves x 16 rows = 128 rows.
// Single-stage: BOTH d-tiles' 6 panels (48KB total, XOR-swizzled) staged
// upfront (6 units/thread, deep MLP), ONE barrier, then both compute phases
// run back-to-back with no further sync.
// Swizzle involution (16B units within a 16x256B panel): unit' = unit^(row&7).
// If out_f32 != nullptr (last layer): write f32 to out_f32 instead of f16 hout.
#define TMG 128
#define NDT 2  // d-tiles per block (grid.y = 8/NDT)
#define MFMA_F16 __builtin_amdgcn_mfma_f32_16x16x32_f16
__global__ __launch_bounds__(512) void gru_fused_kernel(
    const f16* __restrict__ agg, const f16* __restrict__ hin, f16* __restrict__ hout,
    const f16* __restrict__ wct, const f16* __restrict__ whh,
    const float* __restrict__ b_ih, const float* __restrict__ b_hh,
    float* __restrict__ out_f32) {
    __shared__ char wlds[NDT * 6 * 4096];  // [dti][panel][16 rows][128 f16], swizzled
    const int tid = threadIdx.x;
    const int lane = tid & 63;
    const int wv = tid >> 6;   // 0..7
    const int fr = lane & 15;  // A row / B col / D col
    const int kg = lane >> 4;  // k-group
    const int m0 = blockIdx.x * TMG;
    const int dt0 = blockIdx.y * NDT;

    int arow = m0 + wv * 16 + fr;
    int arc = arow < NN ? arow : NN - 1;
    const int abase = arc * D;

    f16x8 fa[4], fh[4];
#pragma unroll
    for (int ks = 0; ks < 4; ++ks) {
        int k0 = ks * 32 + kg * 8;
        fa[ks] = *(const f16x8*)(agg + abase + k0);
        fh[ks] = *(const f16x8*)(hin + abase + k0);
    }

    // Stage NDT*6 panels (NDT*1536 16B units) with 512 threads: 6 units each.
#pragma unroll
    for (int p6 = 0; p6 < NDT * 3; ++p6) {
        int unit = tid + p6 * 512;       // 0..3071
        int dpanel = unit >> 8;          // 0..11
        int dti = dpanel / 6;
        int panel = dpanel % 6;
        int u = unit & 255;
        int sr = u >> 4;                 // row 0..15
        int sc = (u & 15) * 8;           // col base (f16)
        int gr = (dt0 + dti) * 16;
        const f16* srcp = (panel < 3)
                              ? wct + (panel * 128 + gr + sr) * D + sc
                              : whh + ((panel - 3) * 128 + gr + sr) * D + sc;
        int wb = (u * 16) ^ ((sr & 7) << 4);
        *(f16x8*)(wlds + dpanel * 4096 + wb) = *(const f16x8*)srcp;
    }
    __syncthreads();

#pragma unroll
    for (int dti = 0; dti < NDT; ++dti) {
        const int gr = (dt0 + dti) * 16;  // weight-row base of this d-tile
        const char* wb0 = wlds + dti * 6 * 4096;
        f32x4 a_ir = {0, 0, 0, 0}, a_iz = {0, 0, 0, 0}, a_in = {0, 0, 0, 0};
        f32x4 a_hr = {0, 0, 0, 0}, a_hz = {0, 0, 0, 0}, a_hn = {0, 0, 0, 0};
#pragma unroll
        for (int ks = 0; ks < 4; ++ks) {
            // unit index of this k-slice; XOR the FULL unit with row&7
            const int kb = fr * 256 + (((ks * 4 + kg) ^ (fr & 7)) << 4);
            f16x8 bir = *(const f16x8*)(wb0 + 0 * 4096 + kb);
            f16x8 biz = *(const f16x8*)(wb0 + 1 * 4096 + kb);
            f16x8 bin = *(const f16x8*)(wb0 + 2 * 4096 + kb);
            f16x8 bhr = *(const f16x8*)(wb0 + 3 * 4096 + kb);
            f16x8 bhz = *(const f16x8*)(wb0 + 4 * 4096 + kb);
            f16x8 bhn = *(const f16x8*)(wb0 + 5 * 4096 + kb);
            a_ir = MFMA_F16(fa[ks], bir, a_ir, 0, 0, 0);
            a_iz = MFMA_F16(fa[ks], biz, a_iz, 0, 0, 0);
            a_in = MFMA_F16(fa[ks], bin, a_in, 0, 0, 0);
            a_hr = MFMA_F16(fh[ks], bhr, a_hr, 0, 0, 0);
            a_hz = MFMA_F16(fh[ks], bhz, a_hz, 0, 0, 0);
            a_hn = MFMA_F16(fh[ks], bhn, a_hn, 0, 0, 0);
        }
        // Epilogue: C/D layout col = lane&15, row = (lane>>4)*4 + j
        const int d = gr + fr;
        float bir_ = b_ih[d], biz_ = b_ih[128 + d], bin_ = b_ih[256 + d];
        float bhr_ = b_hh[d], bhz_ = b_hh[128 + d], bhn_ = b_hh[256 + d];
#pragma unroll
        for (int j = 0; j < 4; ++j) {
            int row = m0 + wv * 16 + kg * 4 + j;
            if (row >= NN) continue;
            float ir = a_ir[j] + bir_, iz = a_iz[j] + biz_, in_ = a_in[j] + bin_;
            float hr = a_hr[j] + bhr_, hz = a_hz[j] + bhz_, hn = a_hn[j] + bhn_;
            float r = 1.f / (1.f + __expf(-(ir + hr)));
            float zz = 1.f / (1.f + __expf(-(iz + hz)));
            float e2 = __expf(2.f * (in_ + r * hn));
            float nn = 1.f - 2.f / (e2 + 1.f);  // tanh
            int off = row * D + d;
            float hold = (float)hin[off];
            float hnew = (1.f - zz) * nn + zz * hold;
            if (out_f32)
                out_f32[off] = hnew;
            else
                hout[off] = (f16)hnew;
        }
    }
}

// Fallback (no ping-pong room): full-D per block, in-place safe, 256 thr.
__global__ __launch_bounds__(256) void gru_fused_fallback(
    const f16* __restrict__ agg, const f16* __restrict__ hin, f16* __restrict__ hout,
    const f16* __restrict__ wct, const f16* __restrict__ whh,
    const float* __restrict__ b_ih, const float* __restrict__ b_hh,
    float* __restrict__ out_f32) {
    const int tid = threadIdx.x;
    const int lane = tid & 63;
    const int wv = tid >> 6;
    const int fr = lane & 15;
    const int kg = lane >> 4;
    const int m0 = blockIdx.x * 64;
    int arow = m0 + wv * 16 + fr;
    int arc = arow < NN ? arow : NN - 1;
    const int abase = arc * D;
    f16x8 fa[4], fh[4];
#pragma unroll
    for (int ks = 0; ks < 4; ++ks) {
        int k0 = ks * 32 + kg * 8;
        fa[ks] = *(const f16x8*)(agg + abase + k0);
        fh[ks] = *(const f16x8*)(hin + abase + k0);
    }
#pragma unroll 1
    for (int dt = 0; dt < 8; ++dt) {
        const int g = dt * 16 + fr;
        f32x4 a_ir = {0, 0, 0, 0}, a_iz = {0, 0, 0, 0}, a_in = {0, 0, 0, 0};
        f32x4 a_hr = {0, 0, 0, 0}, a_hz = {0, 0, 0, 0}, a_hn = {0, 0, 0, 0};
#pragma unroll
        for (int ks = 0; ks < 4; ++ks) {
            int k0 = ks * 32 + kg * 8;
            f16x8 bir = *(const f16x8*)(wct + (g)*D + k0);
            f16x8 biz = *(const f16x8*)(wct + (128 + g) * D + k0);
            f16x8 bin = *(const f16x8*)(wct + (256 + g) * D + k0);
            f16x8 bhr = *(const f16x8*)(whh + (g)*D + k0);
            f16x8 bhz = *(const f16x8*)(whh + (128 + g) * D + k0);
            f16x8 bhn = *(const f16x8*)(whh + (256 + g) * D + k0);
            a_ir = MFMA_F16(fa[ks], bir, a_ir, 0, 0, 0);
            a_iz = MFMA_F16(fa[ks], biz, a_iz, 0, 0, 0);
            a_in = MFMA_F16(fa[ks], bin, a_in, 0, 0, 0);
            a_hr = MFMA_F16(fh[ks], bhr, a_hr, 0, 0, 0);
            a_hz = MFMA_F16(fh[ks], bhz, a_hz, 0, 0, 0);
            a_hn = MFMA_F16(fh[ks], bhn, a_hn, 0, 0, 0);
        }
        const int d = g;
        float bir_ = b_ih[d], biz_ = b_ih[128 + d], bin_ = b_ih[256 + d];
        float bhr_ = b_hh[d], bhz_ = b_hh[128 + d], bhn_ = b_hh[256 + d];
#pragma unroll
        for (int j = 0; j < 4; ++j) {
            int row = m0 + wv * 16 + kg * 4 + j;
            if (row >= NN) continue;
            float ir = a_ir[j] + bir_, iz = a_iz[j] + biz_, in_ = a_in[j] + bin_;
            float hr = a_hr[j] + bhr_, hz = a_hz[j] + bhz_, hn = a_hn[j] + bhn_;
            float r = 1.f / (1.f + __expf(-(ir + hr)));
            float zz = 1.f / (1.f + __expf(-(iz + hz)));
            float e2 = __expf(2.f * (in_ + r * hn));
            float nn = 1.f - 2.f / (e2 + 1.f);
            int off = row * D + d;
            float hold = (float)hin[off];
            float hnew = (1.f - zz) * nn + zz * hold;
            if (out_f32)
                out_f32[off] = hnew;
            else
                hout[off] = (f16)hnew;
        }
    }
}

// ---------------------------------------------------------------------------
extern "C" void kernel_launch(void* const* d_in, const int* in_sizes, int n_in,
                              void* d_out, int out_size, void* d_ws, size_t ws_size,
                              hipStream_t stream) {
    const float* z = (const float*)d_in[0];
    const int* ei = (const int*)d_in[1];
    const float* weight = (const float*)d_in[2];
    const float* w_ih = (const float*)d_in[3];
    const float* w_hh = (const float*)d_in[4];
    const float* b_ih = (const float*)d_in[5];
    const float* b_hh = (const float*)d_in[6];
    float* out = (float*)d_out;

    char* ws = (char*)d_ws;
    size_t off = 0;
    f16* wct = (f16*)(ws + off); off += 294912;
    f16* whh = (f16*)(ws + off); off += 98304;
    int* flag       = (int*)(ws + off); off += 256;
    int* counts     = (int*)(ws + off); off += (size_t)NN * 4;
    int* row_start  = (int*)(ws + off); off += (size_t)(NN + 16) * 4;
    int* block_sums = (int*)(ws + off); off += (size_t)NSB * 4;
    int* block_off  = (int*)(ws + off); off += (size_t)NSB * 4;
    unsigned short* rank16 = (unsigned short*)(ws + off); off += (size_t)NE * 2;
    unsigned short* csr16  = (unsigned short*)(ws + off); off += (size_t)NE * 2;
    f16* agg  = (f16*)(ws + off); off += (size_t)NN * D * 2;
    f16* hA   = (f16*)(ws + off); off += (size_t)NN * D * 2;
    f16* hB   = (f16*)(ws + off); off += (size_t)NN * D * 2;
    const bool split = (ws_size >= off);  // room for ping-pong buffer?
    if (!split) hB = hA;

    detect_i64_kernel<<<1, 256, 0, stream>>>(ei, flag);
    hipMemsetAsync(counts, 0, (size_t)NN * 4, stream);
    hist_kernel<<<(NE + 255) / 256, 256, 0, stream>>>(ei, flag, counts, rank16);
    scan_reduce_kernel<<<NSB, SBLK, 0, stream>>>(counts, block_sums);
    scan_offsets_kernel<<<1, 256, 0, stream>>>(block_sums, block_off, row_start);
    scan_final_kernel<<<NSB, SBLK, 0, stream>>>(counts, block_off, row_start);
    fill_kernel<<<(NE + 255) / 256, 256, 0, stream>>>(ei, flag, row_start, rank16, csr16);
    precompute_weights<<<NL * G3, 128, 0, stream>>>(weight, w_ih, w_hh, wct, whh);
    const int npair = NN * D / 2;
    init_h_kernel<<<(npair + 255) / 256, 256, 0, stream>>>(z, hA);

    const dim3 gg((NN + TMG - 1) / TMG, 8 / NDT);
    const f16* cin = hA;
    for (int l = 0; l < NL; ++l) {
        gather_kernel<<<(NN + 3) / 4, 256, 0, stream>>>(cin, row_start, csr16, agg);
        f16* cout = split ? ((cin == hA) ? hB : hA) : (f16*)cin;
        long long woff = (long long)l * G3 * D;
        float* last_out = (l == NL - 1) ? out : nullptr;
        if (split) {
            gru_fused_kernel<<<gg, 512, 0, stream>>>(agg, cin, cout, wct + woff, whh,
                                                     b_ih, b_hh, last_out);
        } else {
            gru_fused_fallback<<<(NN + 63) / 64, 256, 0, stream>>>(
                agg, cin, cout, wct + woff, whh, b_ih, b_hh, last_out);
        }
        cin = cout;
    }
}